// Round 3
// baseline (2213.926 us; speedup 1.0000x reference)
//
#include <hip/hip_runtime.h>

typedef unsigned short ushort_t;
typedef __attribute__((ext_vector_type(8))) short bh8;
typedef __attribute__((ext_vector_type(4))) float f32x4;

#define DIM 256
#define DI 512
#define DS 16
#define DTR 16
#define LEN 2048
#define BATCH 16
#define NROW (BATCH * LEN)   // 32768

__device__ __forceinline__ float b2f(ushort_t u) {
    union { unsigned int i; float f; } v; v.i = ((unsigned int)u) << 16; return v.f;
}
__device__ __forceinline__ ushort_t f2b(float f) {
    union { float ff; unsigned int i; } v; v.ff = f;
    unsigned int x = v.i;
    x += 0x7fffu + ((x >> 16) & 1u);
    return (ushort_t)(x >> 16);
}
// load 8 consecutive fp32, round to 8 bf16
__device__ __forceinline__ bh8 cvt8(const float* p) {
    const f32x4 a = *(const f32x4*)p;
    const f32x4 b = *(const f32x4*)(p + 4);
    bh8 r;
    r[0] = (short)f2b(a[0]); r[1] = (short)f2b(a[1]);
    r[2] = (short)f2b(a[2]); r[3] = (short)f2b(a[3]);
    r[4] = (short)f2b(b[0]); r[5] = (short)f2b(b[1]);
    r[6] = (short)f2b(b[2]); r[7] = (short)f2b(b[3]);
    return r;
}

// ---------------- LayerNorm + channel swap (fp32 in -> bf16 out) ----------------
// x1n = LN(x1,ln1), x2n = LN(x2,ln2); xs1 = [x2n[:nc] | x1n[nc:]]; xs2 = x2n
__global__ __launch_bounds__(256) void ln_swap_kernel(
    const float* __restrict__ x1, const float* __restrict__ x2,
    const float* __restrict__ ratio,
    const float* __restrict__ ln1w, const float* __restrict__ ln1b,
    const float* __restrict__ ln2w, const float* __restrict__ ln2b,
    ushort_t* __restrict__ xs1, ushort_t* __restrict__ xs2) {
    const int m = blockIdx.x;
    const int c = threadIdx.x;
    const size_t off = (size_t)m * DIM + c;
    float v1 = x1[off];
    float v2 = x2[off];
    float s1 = v1, q1 = v1 * v1, s2 = v2, q2 = v2 * v2;
    #pragma unroll
    for (int o = 32; o; o >>= 1) {
        s1 += __shfl_xor(s1, o); q1 += __shfl_xor(q1, o);
        s2 += __shfl_xor(s2, o); q2 += __shfl_xor(q2, o);
    }
    __shared__ float red[4][4];
    const int w = threadIdx.x >> 6;
    if ((threadIdx.x & 63) == 0) { red[w][0] = s1; red[w][1] = q1; red[w][2] = s2; red[w][3] = q2; }
    __syncthreads();
    s1 = red[0][0] + red[1][0] + red[2][0] + red[3][0];
    q1 = red[0][1] + red[1][1] + red[2][1] + red[3][1];
    s2 = red[0][2] + red[1][2] + red[2][2] + red[3][2];
    q2 = red[0][3] + red[1][3] + red[2][3] + red[3][3];
    const float inv = 1.0f / DIM;
    float mu1 = s1 * inv, mu2 = s2 * inv;
    float r1 = rsqrtf(q1 * inv - mu1 * mu1 + 1e-5f);
    float r2 = rsqrtf(q2 * inv - mu2 * mu2 + 1e-5f);
    float n1 = (v1 - mu1) * r1 * ln1w[c] + ln1b[c];
    float n2 = (v2 - mu2) * r2 * ln2w[c] + ln2b[c];
    int nc = (int)(DIM / (1.0f + expf(-ratio[0])));   // = 159
    xs2[off] = f2b(n2);
    xs1[off] = f2b(c < nc ? n2 : n1);
}

// ---------------- MFMA GEMM: C = A @ W^T, A:(M,K) bf16 scratch, W:(N,K) fp32 ----------------
// EPI 0: split store to u (n<512) / z (n>=512), bf16
// EPI 1: store f32 to dbl (N=48)
// EPI 2: store f32 + residual(f32) to d_out
template <int BM, int BN, int WM, int WN, int EPI>
__global__ __launch_bounds__(256) void gemm_bt(
    const ushort_t* __restrict__ A0, const ushort_t* __restrict__ A1,
    const float* __restrict__ W0, const float* __restrict__ W1,
    void* __restrict__ oa0, void* __restrict__ oa1,
    ushort_t* __restrict__ ob0, ushort_t* __restrict__ ob1,
    const float* __restrict__ r0, const float* __restrict__ r1,
    int M, int N, int K, int ebase) {
    constexpr int BK = 32;
    constexpr int LDT = BK + 8;   // bf16 elems per LDS row (80B -> 2-way bank alias only, free)
    constexpr int NWN = BN / WN;
    constexpr int MR = WM / 16, NR = WN / 16;

    const int e = ebase + blockIdx.z;
    const ushort_t* __restrict__ A = e ? A1 : A0;
    const float* __restrict__ W = e ? W1 : W0;
    const int m0 = blockIdx.x * BM;
    const int n0 = blockIdx.y * BN;
    const int tid = threadIdx.x;
    const int lane = tid & 63, wid = tid >> 6;
    const int wr = wid / NWN, wc = wid % NWN;
    const int lrow = tid >> 2;          // 64 rows per pass
    const int lcol = (tid & 3) * 8;

    __shared__ ushort_t sA[BM * LDT];
    __shared__ ushort_t sW[BN * LDT];

    f32x4 acc[MR][NR];
    #pragma unroll
    for (int i = 0; i < MR; i++)
        #pragma unroll
        for (int j = 0; j < NR; j++)
            acc[i][j] = (f32x4){0.f, 0.f, 0.f, 0.f};

    for (int kt = 0; kt < K; kt += BK) {
        __syncthreads();
        #pragma unroll
        for (int r = 0; r < BM; r += 64) {
            int row = r + lrow;
            bh8 v = *(const bh8*)(A + (size_t)(m0 + row) * K + kt + lcol);
            *(bh8*)(&sA[row * LDT + lcol]) = v;
        }
        #pragma unroll
        for (int r = 0; r < BN; r += 64) {
            int row = r + lrow;
            if (row < BN) {
                bh8 v = cvt8(W + (size_t)(n0 + row) * K + kt + lcol);
                *(bh8*)(&sW[row * LDT + lcol]) = v;
            }
        }
        __syncthreads();
        bh8 af[MR], wf[NR];
        #pragma unroll
        for (int i = 0; i < MR; i++)
            af[i] = *(const bh8*)(&sA[(wr * WM + i * 16 + (lane & 15)) * LDT + (lane >> 4) * 8]);
        #pragma unroll
        for (int j = 0; j < NR; j++)
            wf[j] = *(const bh8*)(&sW[(wc * WN + j * 16 + (lane & 15)) * LDT + (lane >> 4) * 8]);
        #pragma unroll
        for (int i = 0; i < MR; i++)
            #pragma unroll
            for (int j = 0; j < NR; j++)
                acc[i][j] = __builtin_amdgcn_mfma_f32_16x16x32_bf16(af[i], wf[j], acc[i][j], 0, 0, 0);
    }

    #pragma unroll
    for (int i = 0; i < MR; i++) {
        #pragma unroll
        for (int j = 0; j < NR; j++) {
            const int rbase = m0 + wr * WM + i * 16 + (lane >> 4) * 4;
            const int col = n0 + wc * WN + j * 16 + (lane & 15);
            #pragma unroll
            for (int r = 0; r < 4; r++) {
                const int row = rbase + r;
                const float v = acc[i][j][r];
                if constexpr (EPI == 0) {
                    ushort_t* u = e ? (ushort_t*)oa1 : (ushort_t*)oa0;
                    ushort_t* z = e ? ob1 : ob0;
                    if (col < DI) u[(size_t)row * DI + col] = f2b(v);
                    else          z[(size_t)row * DI + (col - DI)] = f2b(v);
                } else if constexpr (EPI == 1) {
                    float* dbl = e ? (float*)oa1 : (float*)oa0;
                    dbl[(size_t)row * 48 + col] = v;
                } else {
                    const float* rr = e ? r1 : r0;
                    float* oo = e ? (float*)oa1 : (float*)oa0;
                    const size_t off = (size_t)row * DIM + col;
                    oo[off] = v + rr[off];
                }
            }
        }
    }
}

// ---------------- causal depthwise conv4 + SiLU (bf16 in/out, fp32 weights) ----------------
__global__ __launch_bounds__(256) void conv_silu_kernel(
    const ushort_t* __restrict__ u0, const ushort_t* __restrict__ u1,
    const float* __restrict__ cw0, const float* __restrict__ cw1,
    const float* __restrict__ cb0, const float* __restrict__ cb1,
    ushort_t* __restrict__ uc0, ushort_t* __restrict__ uc1, int ebase) {
    const int e = ebase + blockIdx.z;
    const ushort_t* __restrict__ u  = e ? u1 : u0;
    const float* __restrict__ cw = e ? cw1 : cw0;
    const float* __restrict__ cb = e ? cb1 : cb0;
    ushort_t* __restrict__ uc = e ? uc1 : uc0;
    const size_t idx = (size_t)blockIdx.x * 256 + threadIdx.x;  // over NROW*DI
    const int d = (int)(idx & (DI - 1));
    const size_t m = idx >> 9;
    const int t = (int)(m & (LEN - 1));
    float acc = cb[d];
    #pragma unroll
    for (int j = 0; j < 4; j++) {
        const int tt = t - 3 + j;
        if (tt >= 0) {
            const long long li = (long long)idx + (long long)(j - 3) * DI;
            acc += cw[(d << 2) + j] * b2f(u[li]);
        }
    }
    const float s = acc / (1.0f + expf(-acc));
    uc[idx] = f2b(s);
}

// ---------------- delta = softplus(dt @ dt_w^T + dt_b) ----------------
__global__ __launch_bounds__(256) void delta_kernel(
    const float* __restrict__ dbl0, const float* __restrict__ dbl1,
    const float* __restrict__ dtw0, const float* __restrict__ dtw1,
    const float* __restrict__ dtb0, const float* __restrict__ dtb1,
    ushort_t* __restrict__ del0, ushort_t* __restrict__ del1, int ebase) {
    const int e = ebase + blockIdx.z;
    const float* __restrict__ dbl = e ? dbl1 : dbl0;
    const float* __restrict__ dtw = e ? dtw1 : dtw0;
    const float* __restrict__ dtb = e ? dtb1 : dtb0;
    ushort_t* __restrict__ del = e ? del1 : del0;
    const size_t idx = (size_t)blockIdx.x * 256 + threadIdx.x;  // over NROW*DI
    const int d = (int)(idx & (DI - 1));
    const size_t m = idx >> 9;
    const float* __restrict__ dr = dbl + m * 48;
    float x = dtb[d];
    #pragma unroll
    for (int k = 0; k < DTR; k++) x += dr[k] * dtw[(d << 4) + k];
    const float sp = (x > 20.0f) ? x : log1pf(expf(x));
    del[idx] = f2b(sp);
}

// ---------------- selective scan (thread per (b,d,s)) + gate fuse ----------------
// NOTE: del and y ALIAS (y[t] written only after del[t] consumed; same wave owns
// the column) -> no __restrict__ on del/y.
__global__ __launch_bounds__(256) void scan_kernel(
    const ushort_t* del0, const ushort_t* del1,
    const ushort_t* __restrict__ uc0, const ushort_t* __restrict__ uc1,
    const float* __restrict__ dbl0, const float* __restrict__ dbl1,
    const ushort_t* __restrict__ z0, const ushort_t* __restrict__ z1,
    const float* __restrict__ al0, const float* __restrict__ al1,
    const float* __restrict__ Dp0, const float* __restrict__ Dp1,
    ushort_t* y0, ushort_t* y1, int ebase) {
    const int e = ebase + blockIdx.z;
    const ushort_t* del = e ? del1 : del0;
    const ushort_t* __restrict__ uc  = e ? uc1 : uc0;
    const float* __restrict__ dbl    = e ? dbl1 : dbl0;
    const ushort_t* __restrict__ zz  = e ? z1 : z0;
    const float* __restrict__ al    = e ? al1 : al0;
    const float* __restrict__ Dq    = e ? Dp1 : Dp0;
    ushort_t* yo                     = e ? y1 : y0;

    const int b = blockIdx.x >> 5;
    const int dtile = blockIdx.x & 31;
    const int s = threadIdx.x & 15;
    const int dloc = threadIdx.x >> 4;
    const int d = dtile * 16 + dloc;

    const float A  = -expf(al[(d << 4) + s]);
    const float A2 = A * 1.44269504f;           // pre-scale by log2(e)
    const float Dp = Dq[d];

    const size_t mbase = (size_t)b * LEN;
    const ushort_t* delp = del + mbase * DI + d;
    const ushort_t* __restrict__ ucp  = uc  + mbase * DI + d;
    const ushort_t* __restrict__ zp   = zz  + mbase * DI + d;
    const float* __restrict__ dblp    = dbl + mbase * 48;
    ushort_t* yp                      = yo  + mbase * DI + d;

    float h = 0.0f;
    float dtc = b2f(delp[0]);
    float utc = b2f(ucp[0]);
    float Bvc = dblp[16 + s];
    float Cvc = dblp[32 + s];

    for (int t = 0; t < LEN; t++) {
        float dtn = 0.f, utn = 0.f, Bvn = 0.f, Cvn = 0.f;
        if (t + 1 < LEN) {                      // prefetch next step
            dtn = b2f(delp[(size_t)(t + 1) * DI]);
            utn = b2f(ucp[(size_t)(t + 1) * DI]);
            Bvn = dblp[(size_t)(t + 1) * 48 + 16 + s];
            Cvn = dblp[(size_t)(t + 1) * 48 + 32 + s];
        }
        const float ex = exp2f(dtc * A2);
        h = h * ex + dtc * utc * Bvc;
        float yv = h * Cvc;
        yv += __shfl_xor(yv, 1);
        yv += __shfl_xor(yv, 2);
        yv += __shfl_xor(yv, 4);
        yv += __shfl_xor(yv, 8);
        if (s == 0) {
            const float zv = b2f(zp[(size_t)t * DI]);
            const float g = zv / (1.0f + expf(-zv));
            yp[(size_t)t * DI] = f2b((yv + utc * Dp) * g);
        }
        dtc = dtn; utc = utn; Bvc = Bvn; Cvc = Cvn;
    }
}

extern "C" void kernel_launch(void* const* d_in, const int* in_sizes, int n_in,
                              void* d_out, int out_size, void* d_ws, size_t ws_size,
                              hipStream_t stream) {
    const float* x1    = (const float*)d_in[0];
    const float* x2    = (const float*)d_in[1];
    const float* ratio = (const float*)d_in[2];
    const float* ln1w  = (const float*)d_in[3];
    const float* ln1b  = (const float*)d_in[4];
    const float* ln2w  = (const float*)d_in[5];
    const float* ln2b  = (const float*)d_in[6];
    const float* inw[2]   = {(const float*)d_in[7],  (const float*)d_in[16]};
    const float* convw[2] = {(const float*)d_in[8],  (const float*)d_in[17]};
    const float* convb[2] = {(const float*)d_in[9],  (const float*)d_in[18]};
    const float* xprw[2]  = {(const float*)d_in[10], (const float*)d_in[19]};
    const float* dtw[2]   = {(const float*)d_in[11], (const float*)d_in[20]};
    const float* dtb[2]   = {(const float*)d_in[12], (const float*)d_in[21]};
    const float* alog[2]  = {(const float*)d_in[13], (const float*)d_in[22]};
    const float* Dp[2]    = {(const float*)d_in[14], (const float*)d_in[23]};
    const float* outw[2]  = {(const float*)d_in[15], (const float*)d_in[24]};

    // d_out is fp32: o1 = floats [0, NROW*DIM), o2 = [NROW*DIM, 2*NROW*DIM).
    // bf16 xs scratch placement inside d_out:
    //   xs[0] -> bytes [0, NROW*DIM*2)           (inside o1's region; xs[0] dead
    //            before o1 is written, in both par and seq modes)
    //   xs[1] -> bytes [NROW*DIM*4, ...)         (start of o2's region; o2 is only
    //            written by encoder 1's out-proj, after xs[1] is consumed)
    float* o1 = (float*)d_out;
    float* o2 = o1 + (size_t)NROW * DIM;
    ushort_t* xs[2];
    xs[0] = (ushort_t*)d_out;
    xs[1] = (ushort_t*)o2;

    const size_t SZ_DI  = ((size_t)NROW * DI * 2 + 255) & ~(size_t)255;  // 33.6 MB
    const size_t SZ_DBL = ((size_t)NROW * 48 * 4 + 255) & ~(size_t)255;  // 6.3 MB
    const size_t NEED_PAR = 2 * (3 * SZ_DI + SZ_DBL);                    // ~214 MB
    const bool par = ws_size >= NEED_PAR;

    // Arena aliasing chain: u (dead after conv) -> del (dead as scan consumes) -> y.
    char* p = (char*)d_ws;
    ushort_t *u[2], *z[2], *uc[2];
    float* dbl[2];
    if (par) {
        u[0]  = (ushort_t*)p;             u[1]  = (ushort_t*)(p + SZ_DI);      p += 2 * SZ_DI;
        z[0]  = (ushort_t*)p;             z[1]  = (ushort_t*)(p + SZ_DI);      p += 2 * SZ_DI;
        uc[0] = (ushort_t*)p;             uc[1] = (ushort_t*)(p + SZ_DI);      p += 2 * SZ_DI;
        dbl[0] = (float*)p;               dbl[1] = (float*)(p + SZ_DBL);
    } else {
        u[0]  = u[1]  = (ushort_t*)p;     p += SZ_DI;
        z[0]  = z[1]  = (ushort_t*)p;     p += SZ_DI;
        uc[0] = uc[1] = (ushort_t*)p;     p += SZ_DI;
        dbl[0] = dbl[1] = (float*)p;
    }
    ushort_t* del[2] = {u[0], u[1]};   // u dead after conv
    ushort_t* yf[2]  = {u[0], u[1]};   // scan writes y[t] after consuming del[t]

    ln_swap_kernel<<<NROW, 256, 0, stream>>>(x1, x2, ratio, ln1w, ln1b, ln2w, ln2b, xs[0], xs[1]);

    const int nz = par ? 2 : 1;
    const int ne = par ? 1 : 2;
    for (int eb = 0; eb < ne; eb++) {
        gemm_bt<128, 128, 64, 64, 0><<<dim3(NROW / 128, 1024 / 128, nz), 256, 0, stream>>>(
            xs[0], xs[1], inw[0], inw[1], u[0], u[1], z[0], z[1], nullptr, nullptr,
            NROW, 2 * DI, DIM, eb);

        conv_silu_kernel<<<dim3((NROW * DI) / 256, 1, nz), 256, 0, stream>>>(
            u[0], u[1], convw[0], convw[1], convb[0], convb[1], uc[0], uc[1], eb);

        gemm_bt<128, 48, 32, 48, 1><<<dim3(NROW / 128, 1, nz), 256, 0, stream>>>(
            uc[0], uc[1], xprw[0], xprw[1], dbl[0], dbl[1], nullptr, nullptr, nullptr, nullptr,
            NROW, 48, DI, eb);

        delta_kernel<<<dim3((NROW * DI) / 256, 1, nz), 256, 0, stream>>>(
            dbl[0], dbl[1], dtw[0], dtw[1], dtb[0], dtb[1], del[0], del[1], eb);

        scan_kernel<<<dim3(BATCH * 32, 1, nz), 256, 0, stream>>>(
            del[0], del[1], uc[0], uc[1], dbl[0], dbl[1], z[0], z[1],
            alog[0], alog[1], Dp[0], Dp[1], yf[0], yf[1], eb);

        gemm_bt<128, 128, 64, 64, 2><<<dim3(NROW / 128, 256 / 128, nz), 256, 0, stream>>>(
            yf[0], yf[1], outw[0], outw[1], o1, o2, nullptr, nullptr, x1, x2,
            NROW, DIM, DI, eb);
    }
}

// Round 4
// 1183.699 us; speedup vs baseline: 1.8703x; 1.8703x over previous
//
#include <hip/hip_runtime.h>

typedef unsigned short ushort_t;
typedef __attribute__((ext_vector_type(8))) short bh8;
typedef __attribute__((ext_vector_type(4))) short bh4;
typedef __attribute__((ext_vector_type(4))) float f32x4;

#define DIM 256
#define DI 512
#define DS 16
#define DTR 16
#define LEN 2048
#define BATCH 16
#define NROW (BATCH * LEN)   // 32768
#define NCHUNK (NROW / 8)    // 4096 8-step chunks per d-channel

__device__ __forceinline__ float b2f(ushort_t u) {
    union { unsigned int i; float f; } v; v.i = ((unsigned int)u) << 16; return v.f;
}
__device__ __forceinline__ ushort_t f2b(float f) {
    union { float ff; unsigned int i; } v; v.ff = f;
    unsigned int x = v.i;
    x += 0x7fffu + ((x >> 16) & 1u);
    return (ushort_t)(x >> 16);
}
// load 8 consecutive fp32, round to 8 bf16
__device__ __forceinline__ bh8 cvt8(const float* p) {
    const f32x4 a = *(const f32x4*)p;
    const f32x4 b = *(const f32x4*)(p + 4);
    bh8 r;
    r[0] = (short)f2b(a[0]); r[1] = (short)f2b(a[1]);
    r[2] = (short)f2b(a[2]); r[3] = (short)f2b(a[3]);
    r[4] = (short)f2b(b[0]); r[5] = (short)f2b(b[1]);
    r[6] = (short)f2b(b[2]); r[7] = (short)f2b(b[3]);
    return r;
}
// sum over each 16-lane DPP row; result valid in lane 15 of the row (VALU-rate, no LDS)
__device__ __forceinline__ float sum16(float v) {
    int x;
    x = __builtin_amdgcn_update_dpp(0, __float_as_int(v), 0x111, 0xf, 0xf, true); v += __int_as_float(x); // row_shr:1
    x = __builtin_amdgcn_update_dpp(0, __float_as_int(v), 0x112, 0xf, 0xf, true); v += __int_as_float(x); // row_shr:2
    x = __builtin_amdgcn_update_dpp(0, __float_as_int(v), 0x114, 0xf, 0xf, true); v += __int_as_float(x); // row_shr:4
    x = __builtin_amdgcn_update_dpp(0, __float_as_int(v), 0x118, 0xf, 0xf, true); v += __int_as_float(x); // row_shr:8
    return v;
}

// ---------------- LayerNorm + channel swap (fp32 in -> bf16 out) ----------------
__global__ __launch_bounds__(256) void ln_swap_kernel(
    const float* __restrict__ x1, const float* __restrict__ x2,
    const float* __restrict__ ratio,
    const float* __restrict__ ln1w, const float* __restrict__ ln1b,
    const float* __restrict__ ln2w, const float* __restrict__ ln2b,
    ushort_t* __restrict__ xs1, ushort_t* __restrict__ xs2) {
    const int m = blockIdx.x;
    const int c = threadIdx.x;
    const size_t off = (size_t)m * DIM + c;
    float v1 = x1[off];
    float v2 = x2[off];
    float s1 = v1, q1 = v1 * v1, s2 = v2, q2 = v2 * v2;
    #pragma unroll
    for (int o = 32; o; o >>= 1) {
        s1 += __shfl_xor(s1, o); q1 += __shfl_xor(q1, o);
        s2 += __shfl_xor(s2, o); q2 += __shfl_xor(q2, o);
    }
    __shared__ float red[4][4];
    const int w = threadIdx.x >> 6;
    if ((threadIdx.x & 63) == 0) { red[w][0] = s1; red[w][1] = q1; red[w][2] = s2; red[w][3] = q2; }
    __syncthreads();
    s1 = red[0][0] + red[1][0] + red[2][0] + red[3][0];
    q1 = red[0][1] + red[1][1] + red[2][1] + red[3][1];
    s2 = red[0][2] + red[1][2] + red[2][2] + red[3][2];
    q2 = red[0][3] + red[1][3] + red[2][3] + red[3][3];
    const float inv = 1.0f / DIM;
    float mu1 = s1 * inv, mu2 = s2 * inv;
    float r1 = rsqrtf(q1 * inv - mu1 * mu1 + 1e-5f);
    float r2 = rsqrtf(q2 * inv - mu2 * mu2 + 1e-5f);
    float n1 = (v1 - mu1) * r1 * ln1w[c] + ln1b[c];
    float n2 = (v2 - mu2) * r2 * ln2w[c] + ln2b[c];
    int nc = (int)(DIM / (1.0f + expf(-ratio[0])));   // = 159
    xs2[off] = f2b(n2);
    xs1[off] = f2b(c < nc ? n2 : n1);
}

// ---------------- MFMA GEMM: C = A @ W^T, A:(M,K) bf16, W:(N,K) fp32 ----------------
// EPI 0: u -> transposed uT[col][m] (bh4 stores), z -> row-major bf16
// EPI 1: dblT[col][m] f32 (transposed, f32x4 stores)
// EPI 2: A is gated on the fly: a = y * silu(z) (z via ob params); out = acc + residual (fp32)
template <int BM, int BN, int WM, int WN, int EPI>
__global__ __launch_bounds__(256) void gemm_bt(
    const ushort_t* __restrict__ A0, const ushort_t* __restrict__ A1,
    const float* __restrict__ W0, const float* __restrict__ W1,
    void* __restrict__ oa0, void* __restrict__ oa1,
    ushort_t* __restrict__ ob0, ushort_t* __restrict__ ob1,
    const float* __restrict__ r0, const float* __restrict__ r1,
    int M, int N, int K, int ebase) {
    constexpr int BK = 32;
    constexpr int LDT = BK + 8;   // 80B rows -> only 2-way bank alias (free)
    constexpr int NWN = BN / WN;
    constexpr int MR = WM / 16, NR = WN / 16;

    const int e = ebase + blockIdx.z;
    const ushort_t* __restrict__ A = e ? A1 : A0;
    const float* __restrict__ W = e ? W1 : W0;
    const int m0 = blockIdx.x * BM;
    const int n0 = blockIdx.y * BN;
    const int tid = threadIdx.x;
    const int lane = tid & 63, wid = tid >> 6;
    const int wr = wid / NWN, wc = wid % NWN;
    const int lrow = tid >> 2;          // 64 rows per pass
    const int lcol = (tid & 3) * 8;

    __shared__ ushort_t sA[BM * LDT];
    __shared__ ushort_t sW[BN * LDT];

    f32x4 acc[MR][NR];
    #pragma unroll
    for (int i = 0; i < MR; i++)
        #pragma unroll
        for (int j = 0; j < NR; j++)
            acc[i][j] = (f32x4){0.f, 0.f, 0.f, 0.f};

    for (int kt = 0; kt < K; kt += BK) {
        __syncthreads();
        #pragma unroll
        for (int r = 0; r < BM; r += 64) {
            int row = r + lrow;
            const size_t off = (size_t)(m0 + row) * K + kt + lcol;
            bh8 v;
            if constexpr (EPI == 2) {       // gate: a = y * silu(z)
                const ushort_t* __restrict__ Zg = e ? ob1 : ob0;
                bh8 yv8 = *(const bh8*)(A + off);
                bh8 zv8 = *(const bh8*)(Zg + off);
                #pragma unroll
                for (int jj = 0; jj < 8; jj++) {
                    const float zf = b2f((ushort_t)zv8[jj]);
                    const float g = zf / (1.0f + expf(-zf));
                    v[jj] = (short)f2b(b2f((ushort_t)yv8[jj]) * g);
                }
            } else {
                v = *(const bh8*)(A + off);
            }
            *(bh8*)(&sA[row * LDT + lcol]) = v;
        }
        #pragma unroll
        for (int r = 0; r < BN; r += 64) {
            int row = r + lrow;
            if (row < BN) {
                bh8 v = cvt8(W + (size_t)(n0 + row) * K + kt + lcol);
                *(bh8*)(&sW[row * LDT + lcol]) = v;
            }
        }
        __syncthreads();
        bh8 af[MR], wf[NR];
        #pragma unroll
        for (int i = 0; i < MR; i++)
            af[i] = *(const bh8*)(&sA[(wr * WM + i * 16 + (lane & 15)) * LDT + (lane >> 4) * 8]);
        #pragma unroll
        for (int j = 0; j < NR; j++)
            wf[j] = *(const bh8*)(&sW[(wc * WN + j * 16 + (lane & 15)) * LDT + (lane >> 4) * 8]);
        #pragma unroll
        for (int i = 0; i < MR; i++)
            #pragma unroll
            for (int j = 0; j < NR; j++)
                acc[i][j] = __builtin_amdgcn_mfma_f32_16x16x32_bf16(af[i], wf[j], acc[i][j], 0, 0, 0);
    }

    #pragma unroll
    for (int i = 0; i < MR; i++) {
        #pragma unroll
        for (int j = 0; j < NR; j++) {
            const int rbase = m0 + wr * WM + i * 16 + (lane >> 4) * 4;
            const int col = n0 + wc * WN + j * 16 + (lane & 15);
            if constexpr (EPI == 0) {
                if (col < DI) {               // u -> transposed uT[col][m], 8B store
                    ushort_t* uT = e ? (ushort_t*)oa1 : (ushort_t*)oa0;
                    bh4 vv;
                    #pragma unroll
                    for (int r = 0; r < 4; r++) vv[r] = (short)f2b(acc[i][j][r]);
                    *(bh4*)(&uT[(size_t)col * NROW + rbase]) = vv;
                } else {                      // z -> row-major bf16
                    ushort_t* z = e ? ob1 : ob0;
                    #pragma unroll
                    for (int r = 0; r < 4; r++)
                        z[(size_t)(rbase + r) * DI + (col - DI)] = f2b(acc[i][j][r]);
                }
            } else if constexpr (EPI == 1) {  // dblT[col][m] f32, 16B store
                float* dblT = e ? (float*)oa1 : (float*)oa0;
                *(f32x4*)(&dblT[(size_t)col * NROW + rbase]) = acc[i][j];
            } else {                          // fp32 out + residual
                const float* rr = e ? r1 : r0;
                float* oo = e ? (float*)oa1 : (float*)oa0;
                #pragma unroll
                for (int r = 0; r < 4; r++) {
                    const size_t off = (size_t)(rbase + r) * DIM + col;
                    oo[off] = acc[i][j][r] + rr[off];
                }
            }
        }
    }
}

// ---------------- causal depthwise conv4 + SiLU, time-major ----------------
// reads uT[d][m], writes ucT[d][m] (bh8) AND uc row-major [m][d] (for x-proj GEMM)
__global__ __launch_bounds__(256) void conv_silu_kernel(
    const ushort_t* __restrict__ uT0, const ushort_t* __restrict__ uT1,
    const float* __restrict__ cw0, const float* __restrict__ cw1,
    const float* __restrict__ cb0, const float* __restrict__ cb1,
    ushort_t* __restrict__ ucT0, ushort_t* __restrict__ ucT1,
    ushort_t* __restrict__ ucR0, ushort_t* __restrict__ ucR1, int ebase) {
    const int e = ebase + blockIdx.z;
    const ushort_t* __restrict__ uT = e ? uT1 : uT0;
    const float* __restrict__ cw = e ? cw1 : cw0;
    const float* __restrict__ cb = e ? cb1 : cb0;
    ushort_t* __restrict__ ucT = e ? ucT1 : ucT0;
    ushort_t* __restrict__ ucR = e ? ucR1 : ucR0;

    const int g = blockIdx.x * 256 + threadIdx.x;   // over 512 * NCHUNK
    const int c = g & (NCHUNK - 1);
    const int d = g >> 12;
    const int b = c >> 8;             // 2048/8 = 256 chunks per batch
    const int t0 = (c & 255) * 8;
    const size_t base = (size_t)d * NROW + b * LEN + t0;

    bh8 cur = *(const bh8*)(uT + base);
    float win[11];
    if (t0) {
        win[0] = b2f(uT[base - 3]); win[1] = b2f(uT[base - 2]); win[2] = b2f(uT[base - 1]);
    } else {
        win[0] = 0.f; win[1] = 0.f; win[2] = 0.f;
    }
    #pragma unroll
    for (int j = 0; j < 8; j++) win[3 + j] = b2f((ushort_t)cur[j]);
    const f32x4 w = *(const f32x4*)(cw + d * 4);
    const float bias = cb[d];
    bh8 o;
    #pragma unroll
    for (int j = 0; j < 8; j++) {
        const float a = bias + w[0] * win[j] + w[1] * win[j + 1] + w[2] * win[j + 2] + w[3] * win[j + 3];
        const float s = a / (1.0f + expf(-a));
        o[j] = (short)f2b(s);
    }
    *(bh8*)(ucT + base) = o;
    const size_t rbase = (size_t)(b * LEN + t0) * DI + d;
    #pragma unroll
    for (int j = 0; j < 8; j++) ucR[rbase + (size_t)j * DI] = (ushort_t)o[j];
}

// ---------------- delta = softplus(dt @ dt_w^T + dt_b), transposed I/O ----------------
// reads dblT[k][m] (k<16), writes delT[d][m]
__global__ __launch_bounds__(256) void delta_kernel(
    const float* __restrict__ dblT0, const float* __restrict__ dblT1,
    const float* __restrict__ dtw0, const float* __restrict__ dtw1,
    const float* __restrict__ dtb0, const float* __restrict__ dtb1,
    ushort_t* __restrict__ delT0, ushort_t* __restrict__ delT1, int ebase) {
    const int e = ebase + blockIdx.z;
    const float* __restrict__ dblT = e ? dblT1 : dblT0;
    const float* __restrict__ dtw = e ? dtw1 : dtw0;
    const float* __restrict__ dtb = e ? dtb1 : dtb0;
    ushort_t* __restrict__ delT = e ? delT1 : delT0;

    const int lane = threadIdx.x & 63, wid = threadIdx.x >> 6;
    const int d = (blockIdx.x & 7) * 64 + lane;
    const int m0 = (((blockIdx.x >> 3) << 2) + wid) * 4;

    const f32x4 w0 = *(const f32x4*)(dtw + d * 16);
    const f32x4 w1 = *(const f32x4*)(dtw + d * 16 + 4);
    const f32x4 w2 = *(const f32x4*)(dtw + d * 16 + 8);
    const f32x4 w3 = *(const f32x4*)(dtw + d * 16 + 12);
    const float bias = dtb[d];
    f32x4 acc = {bias, bias, bias, bias};
    #pragma unroll
    for (int k = 0; k < 16; k++) {
        const f32x4 bv = *(const f32x4*)(dblT + (size_t)k * NROW + m0);
        const float wk = (k < 4) ? w0[k] : (k < 8) ? w1[k - 4] : (k < 12) ? w2[k - 8] : w3[k - 12];
        acc += wk * bv;
    }
    bh4 r;
    #pragma unroll
    for (int mm = 0; mm < 4; mm++) {
        const float x = acc[mm];
        const float sp = (x > 20.0f) ? x : log1pf(expf(x));
        r[mm] = (short)f2b(sp);
    }
    *(bh4*)(&delT[(size_t)d * NROW + m0]) = r;
}

// ---------------- selective scan: time-major inputs, 8-step batches, DPP reduce ----------------
// writes yraw = y_scan + u*Dp (row-major bf16); gate applied in out-proj staging.
__global__ __launch_bounds__(256) void scan_kernel(
    const ushort_t* __restrict__ delT0, const ushort_t* __restrict__ delT1,
    const ushort_t* __restrict__ ucT0, const ushort_t* __restrict__ ucT1,
    const float* __restrict__ dblT0, const float* __restrict__ dblT1,
    const float* __restrict__ al0, const float* __restrict__ al1,
    const float* __restrict__ Dp0, const float* __restrict__ Dp1,
    ushort_t* __restrict__ y0, ushort_t* __restrict__ y1, int ebase) {
    const int e = ebase + blockIdx.z;
    const ushort_t* __restrict__ delT = e ? delT1 : delT0;
    const ushort_t* __restrict__ ucT  = e ? ucT1 : ucT0;
    const float* __restrict__ dblT    = e ? dblT1 : dblT0;
    const float* __restrict__ al      = e ? al1 : al0;
    const float* __restrict__ Dq      = e ? Dp1 : Dp0;
    ushort_t* __restrict__ yo         = e ? y1 : y0;

    const int b = blockIdx.x >> 5;
    const int dtile = blockIdx.x & 31;
    const int tid = threadIdx.x;
    const int s = tid & 15;
    const int d = dtile * 16 + (tid >> 4);   // one d per 16-lane DPP row

    const float A2 = -expf(al[(d << 4) + s]) * 1.44269504f;
    const float Dpv = Dq[d];

    const ushort_t* dT = delT + (size_t)d * NROW + b * LEN;
    const ushort_t* uT = ucT + (size_t)d * NROW + b * LEN;
    const float* Bp = dblT + (size_t)(16 + s) * NROW + b * LEN;
    const float* Cp = dblT + (size_t)(32 + s) * NROW + b * LEN;
    ushort_t* yp = yo + (size_t)b * LEN * DI + d;
    const bool writer = (s == 15);           // DPP row_shr sum lands in lane 15

    float h = 0.f;
    bh8 dv = *(const bh8*)dT;
    bh8 uv = *(const bh8*)uT;
    f32x4 B0 = *(const f32x4*)Bp, B1 = *(const f32x4*)(Bp + 4);
    f32x4 C0 = *(const f32x4*)Cp, C1 = *(const f32x4*)(Cp + 4);

    for (int t0 = 0; t0 < LEN; t0 += 8) {
        bh8 dn = {0,0,0,0,0,0,0,0}, un = {0,0,0,0,0,0,0,0};
        f32x4 Bn0 = {0.f,0.f,0.f,0.f}, Bn1 = Bn0, Cn0 = Bn0, Cn1 = Bn0;
        if (t0 + 8 < LEN) {                  // prefetch next 8-step block
            dn = *(const bh8*)(dT + t0 + 8);
            un = *(const bh8*)(uT + t0 + 8);
            Bn0 = *(const f32x4*)(Bp + t0 + 8); Bn1 = *(const f32x4*)(Bp + t0 + 12);
            Cn0 = *(const f32x4*)(Cp + t0 + 8); Cn1 = *(const f32x4*)(Cp + t0 + 12);
        }
        float yv[8], uf[8];
        #pragma unroll
        for (int j = 0; j < 8; j++) {
            const float dt = b2f((ushort_t)dv[j]);
            uf[j] = b2f((ushort_t)uv[j]);
            const float Bj = (j < 4) ? B0[j] : B1[j - 4];
            const float Cj = (j < 4) ? C0[j] : C1[j - 4];
            h = fmaf(h, exp2f(dt * A2), dt * uf[j] * Bj);
            yv[j] = h * Cj;
        }
        #pragma unroll
        for (int j = 0; j < 8; j++) yv[j] = sum16(yv[j]);   // 8 independent DPP chains
        if (writer) {
            #pragma unroll
            for (int j = 0; j < 8; j++)
                yp[(size_t)(t0 + j) * DI] = f2b(fmaf(uf[j], Dpv, yv[j]));
        }
        dv = dn; uv = un; B0 = Bn0; B1 = Bn1; C0 = Cn0; C1 = Cn1;
    }
}

extern "C" void kernel_launch(void* const* d_in, const int* in_sizes, int n_in,
                              void* d_out, int out_size, void* d_ws, size_t ws_size,
                              hipStream_t stream) {
    const float* x1    = (const float*)d_in[0];
    const float* x2    = (const float*)d_in[1];
    const float* ratio = (const float*)d_in[2];
    const float* ln1w  = (const float*)d_in[3];
    const float* ln1b  = (const float*)d_in[4];
    const float* ln2w  = (const float*)d_in[5];
    const float* ln2b  = (const float*)d_in[6];
    const float* inw[2]   = {(const float*)d_in[7],  (const float*)d_in[16]};
    const float* convw[2] = {(const float*)d_in[8],  (const float*)d_in[17]};
    const float* convb[2] = {(const float*)d_in[9],  (const float*)d_in[18]};
    const float* xprw[2]  = {(const float*)d_in[10], (const float*)d_in[19]};
    const float* dtw[2]   = {(const float*)d_in[11], (const float*)d_in[20]};
    const float* dtb[2]   = {(const float*)d_in[12], (const float*)d_in[21]};
    const float* alog[2]  = {(const float*)d_in[13], (const float*)d_in[22]};
    const float* Dp[2]    = {(const float*)d_in[14], (const float*)d_in[23]};
    const float* outw[2]  = {(const float*)d_in[15], (const float*)d_in[24]};

    // d_out (fp32): o1 | o2. bf16 xs scratch: xs[0] in o1's region (dead before o1
    // written), xs[1] at start of o2's region (o2 written after xs[1] consumed).
    float* o1 = (float*)d_out;
    float* o2 = o1 + (size_t)NROW * DIM;
    ushort_t* xs[2];
    xs[0] = (ushort_t*)d_out;
    xs[1] = (ushort_t*)o2;

    const size_t SZ_DI  = ((size_t)NROW * DI * 2 + 255) & ~(size_t)255;  // 33.6 MB
    const size_t SZ_DBL = ((size_t)NROW * 48 * 4 + 255) & ~(size_t)255;  // 6.3 MB
    const size_t NEED_PAR = 2 * (4 * SZ_DI + SZ_DBL);                    // ~281 MB
    const bool par = ws_size >= NEED_PAR;

    // Arenas: uT -> delT (uT dead after conv); ucR -> y (ucR dead after x-proj).
    char* p = (char*)d_ws;
    ushort_t *uT[2], *z[2], *ucT[2], *ucR[2];
    float* dblT[2];
    if (par) {
        uT[0]  = (ushort_t*)p;          uT[1]  = (ushort_t*)(p + SZ_DI);   p += 2 * SZ_DI;
        z[0]   = (ushort_t*)p;          z[1]   = (ushort_t*)(p + SZ_DI);   p += 2 * SZ_DI;
        ucT[0] = (ushort_t*)p;          ucT[1] = (ushort_t*)(p + SZ_DI);   p += 2 * SZ_DI;
        ucR[0] = (ushort_t*)p;          ucR[1] = (ushort_t*)(p + SZ_DI);   p += 2 * SZ_DI;
        dblT[0] = (float*)p;            dblT[1] = (float*)(p + SZ_DBL);
    } else {
        uT[0]  = uT[1]  = (ushort_t*)p; p += SZ_DI;
        z[0]   = z[1]   = (ushort_t*)p; p += SZ_DI;
        ucT[0] = ucT[1] = (ushort_t*)p; p += SZ_DI;
        ucR[0] = ucR[1] = (ushort_t*)p; p += SZ_DI;
        dblT[0] = dblT[1] = (float*)p;
    }
    ushort_t* delT[2] = {uT[0], uT[1]};
    ushort_t* yf[2]   = {ucR[0], ucR[1]};

    ln_swap_kernel<<<NROW, 256, 0, stream>>>(x1, x2, ratio, ln1w, ln1b, ln2w, ln2b, xs[0], xs[1]);

    const int nz = par ? 2 : 1;
    const int ne = par ? 1 : 2;
    for (int eb = 0; eb < ne; eb++) {
        gemm_bt<128, 128, 64, 64, 0><<<dim3(NROW / 128, 1024 / 128, nz), 256, 0, stream>>>(
            xs[0], xs[1], inw[0], inw[1], uT[0], uT[1], z[0], z[1], nullptr, nullptr,
            NROW, 2 * DI, DIM, eb);

        conv_silu_kernel<<<dim3((DI * NCHUNK) / 256, 1, nz), 256, 0, stream>>>(
            uT[0], uT[1], convw[0], convw[1], convb[0], convb[1],
            ucT[0], ucT[1], ucR[0], ucR[1], eb);

        gemm_bt<128, 48, 32, 48, 1><<<dim3(NROW / 128, 1, nz), 256, 0, stream>>>(
            ucR[0], ucR[1], xprw[0], xprw[1], dblT[0], dblT[1], nullptr, nullptr, nullptr, nullptr,
            NROW, 48, DI, eb);

        delta_kernel<<<dim3(8 * (NROW / 16), 1, nz), 256, 0, stream>>>(
            dblT[0], dblT[1], dtw[0], dtw[1], dtb[0], dtb[1], delT[0], delT[1], eb);

        scan_kernel<<<dim3(BATCH * 32, 1, nz), 256, 0, stream>>>(
            delT[0], delT[1], ucT[0], ucT[1], dblT[0], dblT[1],
            alog[0], alog[1], Dp[0], Dp[1], yf[0], yf[1], eb);

        gemm_bt<128, 128, 64, 64, 2><<<dim3(NROW / 128, 256 / 128, nz), 256, 0, stream>>>(
            yf[0], yf[1], outw[0], outw[1], o1, o2, z[0], z[1], x1, x2,
            NROW, DIM, DI, eb);
    }
}

// Round 5
// 1097.482 us; speedup vs baseline: 2.0173x; 1.0786x over previous
//
#include <hip/hip_runtime.h>

typedef unsigned short ushort_t;
typedef __attribute__((ext_vector_type(8))) short bh8;
typedef __attribute__((ext_vector_type(4))) short bh4;
typedef __attribute__((ext_vector_type(4))) float f32x4;

#define DIM 256
#define DI 512
#define LEN 2048
#define BATCH 16
#define NROW (BATCH * LEN)   // 32768
#define NCHUNK (NROW / 8)

__device__ __forceinline__ float b2f(ushort_t u) {
    union { unsigned int i; float f; } v; v.i = ((unsigned int)u) << 16; return v.f;
}
__device__ __forceinline__ ushort_t f2b(float f) {
    union { float ff; unsigned int i; } v; v.ff = f;
    unsigned int x = v.i;
    x += 0x7fffu + ((x >> 16) & 1u);
    return (ushort_t)(x >> 16);
}
__device__ __forceinline__ void gload16(const ushort_t* g, ushort_t* l) {
    __builtin_amdgcn_global_load_lds((const __attribute__((address_space(1))) unsigned int*)g,
                                     (__attribute__((address_space(3))) unsigned int*)l, 16, 0, 0);
}
// 16-lane butterfly sum via fused DPP adds; ALL lanes end with the row sum
__device__ __forceinline__ float bsum16(float v) {
    int x;
    x = __builtin_amdgcn_update_dpp(0, __float_as_int(v), 0xB1, 0xf, 0xf, true); v += __int_as_float(x); // quad_perm [1,0,3,2]
    x = __builtin_amdgcn_update_dpp(0, __float_as_int(v), 0x4E, 0xf, 0xf, true); v += __int_as_float(x); // quad_perm [2,3,0,1]
    x = __builtin_amdgcn_update_dpp(0, __float_as_int(v), 0x141, 0xf, 0xf, true); v += __int_as_float(x); // row_half_mirror
    x = __builtin_amdgcn_update_dpp(0, __float_as_int(v), 0x140, 0xf, 0xf, true); v += __int_as_float(x); // row_mirror
    return v;
}

// ---------------- LayerNorm + channel swap (fp32 in -> bf16 out) ----------------
__global__ __launch_bounds__(256) void ln_swap_kernel(
    const float* __restrict__ x1, const float* __restrict__ x2,
    const float* __restrict__ ratio,
    const float* __restrict__ ln1w, const float* __restrict__ ln1b,
    const float* __restrict__ ln2w, const float* __restrict__ ln2b,
    ushort_t* __restrict__ xs1, ushort_t* __restrict__ xs2) {
    const int m = blockIdx.x;
    const int c = threadIdx.x;
    const size_t off = (size_t)m * DIM + c;
    float v1 = x1[off];
    float v2 = x2[off];
    float s1 = v1, q1 = v1 * v1, s2 = v2, q2 = v2 * v2;
    #pragma unroll
    for (int o = 32; o; o >>= 1) {
        s1 += __shfl_xor(s1, o); q1 += __shfl_xor(q1, o);
        s2 += __shfl_xor(s2, o); q2 += __shfl_xor(q2, o);
    }
    __shared__ float red[4][4];
    const int w = threadIdx.x >> 6;
    if ((threadIdx.x & 63) == 0) { red[w][0] = s1; red[w][1] = q1; red[w][2] = s2; red[w][3] = q2; }
    __syncthreads();
    s1 = red[0][0] + red[1][0] + red[2][0] + red[3][0];
    q1 = red[0][1] + red[1][1] + red[2][1] + red[3][1];
    s2 = red[0][2] + red[1][2] + red[2][2] + red[3][2];
    q2 = red[0][3] + red[1][3] + red[2][3] + red[3][3];
    const float inv = 1.0f / DIM;
    float mu1 = s1 * inv, mu2 = s2 * inv;
    float r1 = rsqrtf(q1 * inv - mu1 * mu1 + 1e-5f);
    float r2 = rsqrtf(q2 * inv - mu2 * mu2 + 1e-5f);
    float n1 = (v1 - mu1) * r1 * ln1w[c] + ln1b[c];
    float n2 = (v2 - mu2) * r2 * ln2w[c] + ln2b[c];
    int nc = (int)(DIM / (1.0f + expf(-ratio[0])));   // = 159
    xs2[off] = f2b(n2);
    xs1[off] = f2b(c < nc ? n2 : n1);
}

// ---------------- convert weights fp32 -> bf16 (once per call) ----------------
// wbf layout: [0,262144) in_w | [262144,286720) xproj_w | [286720,417792) out_w
#define WB_IN 0
#define WB_XP 262144
#define WB_OUT 286720
#define WB_TOT 417792
__global__ __launch_bounds__(256) void cvtw_kernel(
    const float* __restrict__ iw0, const float* __restrict__ iw1,
    const float* __restrict__ xw0, const float* __restrict__ xw1,
    const float* __restrict__ ow0, const float* __restrict__ ow1,
    ushort_t* __restrict__ o0, ushort_t* __restrict__ o1) {
    const int e = blockIdx.z;
    const float* iw = e ? iw1 : iw0;
    const float* xw = e ? xw1 : xw0;
    const float* ow = e ? ow1 : ow0;
    ushort_t* o = e ? o1 : o0;
    const int idx = blockIdx.x * 256 + threadIdx.x;
    if (idx < WB_XP) o[idx] = f2b(iw[idx]);
    else if (idx < WB_OUT) o[idx] = f2b(xw[idx - WB_XP]);
    else if (idx < WB_TOT) o[idx] = f2b(ow[idx - WB_OUT]);
}

// ---------------- in-proj GEMM: [u|z] = xs @ in_w^T ; outputs TRANSPOSED ----------------
// A: xs (M=NROW, K=256) bf16 row-major; W: winb (N=1024, K=256) bf16 row-major
// uT[col][m] for col<512, zT[col-512][m] otherwise (bh4 stores)
__global__ __launch_bounds__(256) void gemm_in_kernel(
    const ushort_t* __restrict__ A0, const ushort_t* __restrict__ A1,
    const ushort_t* __restrict__ Wb0, const ushort_t* __restrict__ Wb1,
    ushort_t* __restrict__ uT0, ushort_t* __restrict__ uT1,
    ushort_t* __restrict__ zT0, ushort_t* __restrict__ zT1) {
    const int e = blockIdx.z;
    const ushort_t* __restrict__ A = e ? A1 : A0;
    const ushort_t* __restrict__ W = e ? Wb1 : Wb0;
    ushort_t* __restrict__ uT = e ? uT1 : uT0;
    ushort_t* __restrict__ zT = e ? zT1 : zT0;
    const int m0 = blockIdx.x * 128;
    const int n0 = blockIdx.y * 128;
    const int tid = threadIdx.x, lane = tid & 63, wv = tid >> 6;
    const int wr = wv >> 1, wc = wv & 1;

    __shared__ ushort_t sA[128 * 32];
    __shared__ ushort_t sW[128 * 32];

    f32x4 acc[4][4];
    #pragma unroll
    for (int i = 0; i < 4; i++)
        #pragma unroll
        for (int j = 0; j < 4; j++) acc[i][j] = (f32x4){0.f, 0.f, 0.f, 0.f};

    const ushort_t* Ap = A + (size_t)(m0 + wv * 32 + (lane >> 2)) * 256 + (lane & 3) * 8;
    const ushort_t* Wp = W + (size_t)(n0 + wv * 32 + (lane >> 2)) * 256 + (lane & 3) * 8;

    for (int kt = 0; kt < 256; kt += 32) {
        __syncthreads();
        gload16(Ap + kt,             &sA[(wv * 32) * 32]);
        gload16(Ap + kt + 16 * 256,  &sA[(wv * 32 + 16) * 32]);
        gload16(Wp + kt,             &sW[(wv * 32) * 32]);
        gload16(Wp + kt + 16 * 256,  &sW[(wv * 32 + 16) * 32]);
        __syncthreads();
        bh8 af[4], wf[4];
        #pragma unroll
        for (int i = 0; i < 4; i++)
            af[i] = *(const bh8*)(&sA[(wr * 64 + i * 16 + (lane & 15)) * 32 + (lane >> 4) * 8]);
        #pragma unroll
        for (int j = 0; j < 4; j++)
            wf[j] = *(const bh8*)(&sW[(wc * 64 + j * 16 + (lane & 15)) * 32 + (lane >> 4) * 8]);
        #pragma unroll
        for (int i = 0; i < 4; i++)
            #pragma unroll
            for (int j = 0; j < 4; j++)
                acc[i][j] = __builtin_amdgcn_mfma_f32_16x16x32_bf16(af[i], wf[j], acc[i][j], 0, 0, 0);
    }

    #pragma unroll
    for (int i = 0; i < 4; i++) {
        #pragma unroll
        for (int j = 0; j < 4; j++) {
            const int rbase = m0 + wr * 64 + i * 16 + (lane >> 4) * 4;
            const int col = n0 + wc * 64 + j * 16 + (lane & 15);
            bh4 vv;
            #pragma unroll
            for (int r = 0; r < 4; r++) vv[r] = (short)f2b(acc[i][j][r]);
            if (col < DI) *(bh4*)(&uT[(size_t)col * NROW + rbase]) = vv;
            else          *(bh4*)(&zT[(size_t)(col - DI) * NROW + rbase]) = vv;
        }
    }
}

// ---------------- causal depthwise conv4 + SiLU, time-major ----------------
__global__ __launch_bounds__(256) void conv_silu_kernel(
    const ushort_t* __restrict__ uT0, const ushort_t* __restrict__ uT1,
    const float* __restrict__ cw0, const float* __restrict__ cw1,
    const float* __restrict__ cb0, const float* __restrict__ cb1,
    ushort_t* __restrict__ ucT0, ushort_t* __restrict__ ucT1) {
    const int e = blockIdx.z;
    const ushort_t* __restrict__ uT = e ? uT1 : uT0;
    const float* __restrict__ cw = e ? cw1 : cw0;
    const float* __restrict__ cb = e ? cb1 : cb0;
    ushort_t* __restrict__ ucT = e ? ucT1 : ucT0;

    const int g = blockIdx.x * 256 + threadIdx.x;   // over DI * NCHUNK
    const int c = g & (NCHUNK - 1);
    const int d = g >> 12;
    const int b = c >> 8;
    const int t0 = (c & 255) * 8;
    const size_t base = (size_t)d * NROW + b * LEN + t0;

    bh8 cur = *(const bh8*)(uT + base);
    float win[11];
    if (t0) {
        win[0] = b2f(uT[base - 3]); win[1] = b2f(uT[base - 2]); win[2] = b2f(uT[base - 1]);
    } else {
        win[0] = 0.f; win[1] = 0.f; win[2] = 0.f;
    }
    #pragma unroll
    for (int j = 0; j < 8; j++) win[3 + j] = b2f((ushort_t)cur[j]);
    const f32x4 w = *(const f32x4*)(cw + d * 4);
    const float bias = cb[d];
    bh8 o;
    #pragma unroll
    for (int j = 0; j < 8; j++) {
        const float a = bias + w[0] * win[j] + w[1] * win[j + 1] + w[2] * win[j + 2] + w[3] * win[j + 3];
        const float s = a / (1.0f + expf(-a));
        o[j] = (short)f2b(s);
    }
    *(bh8*)(ucT + base) = o;
}

// ---------------- x-proj GEMM: dblT[n][m] = xprw @ ucT (n<48) ----------------
// A-operand = W (48x512 bf16 row-major, reg-staged, padded LDS)
// B-operand = ucT tile (32k x 128m), scatter-transposed into sB[128][40]
__global__ __launch_bounds__(256) void gemm_xp_kernel(
    const ushort_t* __restrict__ ucT0, const ushort_t* __restrict__ ucT1,
    const ushort_t* __restrict__ Wb0, const ushort_t* __restrict__ Wb1,
    float* __restrict__ dbl0, float* __restrict__ dbl1) {
    const int e = blockIdx.z;
    const ushort_t* __restrict__ ucT = e ? ucT1 : ucT0;
    const ushort_t* __restrict__ W = (e ? Wb1 : Wb0) + WB_XP;
    float* __restrict__ dbl = e ? dbl1 : dbl0;
    const int m0 = blockIdx.x * 128;
    const int tid = threadIdx.x, lane = tid & 63;
    const int wc = tid >> 6;           // wave -> m 32-col slice

    __shared__ ushort_t sW[48 * 40];
    __shared__ ushort_t sB[128 * 40];

    f32x4 acc[3][2];
    #pragma unroll
    for (int i = 0; i < 3; i++)
        #pragma unroll
        for (int j = 0; j < 2; j++) acc[i][j] = (f32x4){0.f, 0.f, 0.f, 0.f};

    const int kk = tid >> 3, mc = (tid & 7) * 16;
    const ushort_t* Bp = ucT + (size_t)kk * NROW + m0 + mc;

    for (int kt = 0; kt < 512; kt += 32) {
        __syncthreads();
        // stage W tile 48x32 (threads 0..191)
        if (tid < 192) {
            const int r = tid >> 2, cc = (tid & 3) * 8;
            bh8 v = *(const bh8*)(W + (size_t)r * 512 + kt + cc);
            *(bh8*)(&sW[r * 40 + cc]) = v;
        }
        // stage ucT tile transposed: sB[m][k]
        bh8 a0 = *(const bh8*)(Bp + (size_t)kt * NROW);
        bh8 a1 = *(const bh8*)(Bp + (size_t)kt * NROW + 8);
        #pragma unroll
        for (int q = 0; q < 8; q++) {
            sB[(mc + q) * 40 + kk] = (ushort_t)a0[q];
            sB[(mc + 8 + q) * 40 + kk] = (ushort_t)a1[q];
        }
        __syncthreads();
        bh8 af[3], wf[2];
        #pragma unroll
        for (int i = 0; i < 3; i++)
            af[i] = *(const bh8*)(&sW[(i * 16 + (lane & 15)) * 40 + (lane >> 4) * 8]);
        #pragma unroll
        for (int j = 0; j < 2; j++)
            wf[j] = *(const bh8*)(&sB[(wc * 32 + j * 16 + (lane & 15)) * 40 + (lane >> 4) * 8]);
        #pragma unroll
        for (int i = 0; i < 3; i++)
            #pragma unroll
            for (int j = 0; j < 2; j++)
                acc[i][j] = __builtin_amdgcn_mfma_f32_16x16x32_bf16(af[i], wf[j], acc[i][j], 0, 0, 0);
    }

    #pragma unroll
    for (int i = 0; i < 3; i++) {
        #pragma unroll
        for (int j = 0; j < 2; j++) {
            const int nb = i * 16 + (lane >> 4) * 4;
            const int mm = m0 + wc * 32 + j * 16 + (lane & 15);
            #pragma unroll
            for (int r = 0; r < 4; r++)
                dbl[(size_t)(nb + r) * NROW + mm] = acc[i][j][r];
        }
    }
}

// ---------------- delta = softplus(dt @ dt_w^T + dt_b), coalesced transposed I/O ----------------
__global__ __launch_bounds__(256) void delta_kernel(
    const float* __restrict__ dblT0, const float* __restrict__ dblT1,
    const float* __restrict__ dtw0, const float* __restrict__ dtw1,
    const float* __restrict__ dtb0, const float* __restrict__ dtb1,
    ushort_t* __restrict__ delT0, ushort_t* __restrict__ delT1) {
    const int e = blockIdx.z;
    const float* __restrict__ dblT = e ? dblT1 : dblT0;
    const float* __restrict__ dtw = e ? dtw1 : dtw0;
    const float* __restrict__ dtb = e ? dtb1 : dtb0;
    ushort_t* __restrict__ delT = e ? delT1 : delT0;

    const int tid = threadIdx.x, lane = tid & 63, wv = tid >> 6;
    const int bx = blockIdx.x;
    const int d = (bx & 127) * 4 + wv;          // wave-uniform d
    const int m0 = (bx >> 7) * 256 + lane * 4;

    const float bias = dtb[d];
    f32x4 acc = {bias, bias, bias, bias};
    #pragma unroll
    for (int k = 0; k < 16; k++) {
        const float wk = dtw[d * 16 + k];
        const f32x4 bv = *(const f32x4*)(dblT + (size_t)k * NROW + m0);
        #pragma unroll
        for (int c = 0; c < 4; c++) acc[c] = fmaf(wk, bv[c], acc[c]);
    }
    bh4 r;
    #pragma unroll
    for (int c = 0; c < 4; c++) {
        const float x = acc[c];
        const float sp = (x > 20.0f) ? x : log1pf(expf(x));
        r[c] = (short)f2b(sp);
    }
    *(bh4*)(&delT[(size_t)d * NROW + m0]) = r;
}

// ---------------- selective scan + gate: writes ygT OVER zT (alias) ----------------
__global__ __launch_bounds__(256) void scan_kernel(
    const ushort_t* __restrict__ delT0, const ushort_t* __restrict__ delT1,
    const ushort_t* __restrict__ ucT0, const ushort_t* __restrict__ ucT1,
    const float* __restrict__ dblT0, const float* __restrict__ dblT1,
    const ushort_t* zT0, const ushort_t* zT1,          // aliases ygT: no restrict
    const float* __restrict__ al0, const float* __restrict__ al1,
    const float* __restrict__ Dp0, const float* __restrict__ Dp1,
    ushort_t* yg0, ushort_t* yg1) {
    const int e = blockIdx.z;
    const ushort_t* __restrict__ delT = e ? delT1 : delT0;
    const ushort_t* __restrict__ ucT  = e ? ucT1 : ucT0;
    const float* __restrict__ dbl     = e ? dblT1 : dblT0;
    const ushort_t* zT                = e ? zT1 : zT0;
    const float* __restrict__ al      = e ? al1 : al0;
    const float* __restrict__ Dq      = e ? Dp1 : Dp0;
    ushort_t* yg                      = e ? yg1 : yg0;

    const int b = blockIdx.x >> 5;
    const int dtile = blockIdx.x & 31;
    const int tid = threadIdx.x;
    const int s = tid & 15;
    const int d = dtile * 16 + (tid >> 4);

    const float A2 = -expf(al[(d << 4) + s]) * 1.44269504f;
    const float Dpv = Dq[d];

    const ushort_t* dT = delT + (size_t)d * NROW + b * LEN;
    const ushort_t* uT = ucT + (size_t)d * NROW + b * LEN;
    const ushort_t* zp = zT + (size_t)d * NROW + b * LEN;
    const float* Bp = dbl + (size_t)(16 + s) * NROW + b * LEN;
    const float* Cp = dbl + (size_t)(32 + s) * NROW + b * LEN;
    ushort_t* yp = yg + (size_t)d * NROW + b * LEN;
    const bool writer = (s == 0);

    float h = 0.f;
    bh8 dv = *(const bh8*)dT;
    bh8 uv = *(const bh8*)uT;
    bh8 zv = *(const bh8*)zp;
    f32x4 B0 = *(const f32x4*)Bp, B1 = *(const f32x4*)(Bp + 4);
    f32x4 C0 = *(const f32x4*)Cp, C1 = *(const f32x4*)(Cp + 4);

    for (int t0 = 0; t0 < LEN; t0 += 8) {
        bh8 dn = {0,0,0,0,0,0,0,0}, un = dn, zn = dn;
        f32x4 Bn0 = {0.f,0.f,0.f,0.f}, Bn1 = Bn0, Cn0 = Bn0, Cn1 = Bn0;
        if (t0 + 8 < LEN) {                  // uniform branch (cheap)
            dn = *(const bh8*)(dT + t0 + 8);
            un = *(const bh8*)(uT + t0 + 8);
            zn = *(const bh8*)(zp + t0 + 8);
            Bn0 = *(const f32x4*)(Bp + t0 + 8); Bn1 = *(const f32x4*)(Bp + t0 + 12);
            Cn0 = *(const f32x4*)(Cp + t0 + 8); Cn1 = *(const f32x4*)(Cp + t0 + 12);
        }
        float yv[8], uf[8];
        #pragma unroll
        for (int j = 0; j < 8; j++) {
            const float dt = b2f((ushort_t)dv[j]);
            uf[j] = b2f((ushort_t)uv[j]);
            const float Bj = (j < 4) ? B0[j] : B1[j - 4];
            const float Cj = (j < 4) ? C0[j] : C1[j - 4];
            h = fmaf(h, exp2f(dt * A2), dt * uf[j] * Bj);
            yv[j] = h * Cj;
        }
        #pragma unroll
        for (int j = 0; j < 8; j++) yv[j] = bsum16(yv[j]);   // all lanes get sum
        bh8 o;
        #pragma unroll
        for (int j = 0; j < 8; j++) {
            const float zf = b2f((ushort_t)zv[j]);
            const float gate = zf / (1.0f + expf(-zf));
            o[j] = (short)f2b((yv[j] + uf[j] * Dpv) * gate);
        }
        if (writer) *(bh8*)(yp + t0) = o;   // overwrites zT[t0..t0+7] AFTER zv consumed
        dv = dn; uv = un; zv = zn; B0 = Bn0; B1 = Bn1; C0 = Cn0; C1 = Cn1;
    }
}

// ---------------- out-proj GEMM: o = yg @ out_w^T + residual (fp32) ----------------
// A-operand from ygT (transposed), scatter-staged into sA[128][40]; W via gload.
__global__ __launch_bounds__(256) void gemm_out_kernel(
    const ushort_t* __restrict__ ygT0, const ushort_t* __restrict__ ygT1,
    const ushort_t* __restrict__ Wb0, const ushort_t* __restrict__ Wb1,
    const float* __restrict__ r0, const float* __restrict__ r1,
    float* __restrict__ o0, float* __restrict__ o1) {
    const int e = blockIdx.z;
    const ushort_t* __restrict__ ygT = e ? ygT1 : ygT0;
    const ushort_t* __restrict__ W = (e ? Wb1 : Wb0) + WB_OUT;
    const float* __restrict__ rr = e ? r1 : r0;
    float* __restrict__ oo = e ? o1 : o0;
    const int m0 = blockIdx.x * 128;
    const int n0 = blockIdx.y * 128;
    const int tid = threadIdx.x, lane = tid & 63, wv = tid >> 6;
    const int wr = wv >> 1, wc = wv & 1;

    __shared__ ushort_t sA[128 * 40];
    __shared__ ushort_t sW[128 * 32];

    f32x4 acc[4][4];
    #pragma unroll
    for (int i = 0; i < 4; i++)
        #pragma unroll
        for (int j = 0; j < 4; j++) acc[i][j] = (f32x4){0.f, 0.f, 0.f, 0.f};

    const int kk = tid >> 3, mc = (tid & 7) * 16;
    const ushort_t* Yp = ygT + (size_t)kk * NROW + m0 + mc;
    const ushort_t* Wp = W + (size_t)(n0 + wv * 32 + (lane >> 2)) * 512 + (lane & 3) * 8;

    for (int kt = 0; kt < 512; kt += 32) {
        __syncthreads();
        gload16(Wp + kt,             &sW[(wv * 32) * 32]);
        gload16(Wp + kt + 16 * 512,  &sW[(wv * 32 + 16) * 32]);
        bh8 a0 = *(const bh8*)(Yp + (size_t)kt * NROW);
        bh8 a1 = *(const bh8*)(Yp + (size_t)kt * NROW + 8);
        #pragma unroll
        for (int q = 0; q < 8; q++) {
            sA[(mc + q) * 40 + kk] = (ushort_t)a0[q];
            sA[(mc + 8 + q) * 40 + kk] = (ushort_t)a1[q];
        }
        __syncthreads();
        bh8 af[4], wf[4];
        #pragma unroll
        for (int i = 0; i < 4; i++)
            af[i] = *(const bh8*)(&sA[(wr * 64 + i * 16 + (lane & 15)) * 40 + (lane >> 4) * 8]);
        #pragma unroll
        for (int j = 0; j < 4; j++)
            wf[j] = *(const bh8*)(&sW[(wc * 64 + j * 16 + (lane & 15)) * 32 + (lane >> 4) * 8]);
        #pragma unroll
        for (int i = 0; i < 4; i++)
            #pragma unroll
            for (int j = 0; j < 4; j++)
                acc[i][j] = __builtin_amdgcn_mfma_f32_16x16x32_bf16(af[i], wf[j], acc[i][j], 0, 0, 0);
    }

    #pragma unroll
    for (int i = 0; i < 4; i++) {
        #pragma unroll
        for (int j = 0; j < 4; j++) {
            const int rbase = m0 + wr * 64 + i * 16 + (lane >> 4) * 4;
            const int col = n0 + wc * 64 + j * 16 + (lane & 15);
            #pragma unroll
            for (int r = 0; r < 4; r++) {
                const size_t off = (size_t)(rbase + r) * DIM + col;
                oo[off] = acc[i][j][r] + rr[off];
            }
        }
    }
}

extern "C" void kernel_launch(void* const* d_in, const int* in_sizes, int n_in,
                              void* d_out, int out_size, void* d_ws, size_t ws_size,
                              hipStream_t stream) {
    const float* x1    = (const float*)d_in[0];
    const float* x2    = (const float*)d_in[1];
    const float* ratio = (const float*)d_in[2];
    const float* ln1w  = (const float*)d_in[3];
    const float* ln1b  = (const float*)d_in[4];
    const float* ln2w  = (const float*)d_in[5];
    const float* ln2b  = (const float*)d_in[6];
    const float* inw[2]   = {(const float*)d_in[7],  (const float*)d_in[16]};
    const float* convw[2] = {(const float*)d_in[8],  (const float*)d_in[17]};
    const float* convb[2] = {(const float*)d_in[9],  (const float*)d_in[18]};
    const float* xprw[2]  = {(const float*)d_in[10], (const float*)d_in[19]};
    const float* dtw[2]   = {(const float*)d_in[11], (const float*)d_in[20]};
    const float* dtb[2]   = {(const float*)d_in[12], (const float*)d_in[21]};
    const float* alog[2]  = {(const float*)d_in[13], (const float*)d_in[22]};
    const float* Dp[2]    = {(const float*)d_in[14], (const float*)d_in[23]};
    const float* outw[2]  = {(const float*)d_in[15], (const float*)d_in[24]};

    // d_out map (fp32 o1 | o2, 33.55 MB each):
    //   xs[0] bf16 @ o1 bytes [0, 16.78M); dbl[0] f32 @ o1 bytes [16.78M, 23.07M)
    //   xs[1] bf16 @ o2 bytes [0, 16.78M); dbl[1] f32 @ o2 bytes [16.78M, 23.07M)
    // all dead before out-proj writes o1/o2.
    float* o1 = (float*)d_out;
    float* o2 = o1 + (size_t)NROW * DIM;
    ushort_t* xs[2] = {(ushort_t*)o1, (ushort_t*)o2};
    const size_t XS_BYTES = (size_t)NROW * DIM * 2;   // 16.78 MB
    float* dbl[2] = {(float*)((char*)o1 + XS_BYTES), (float*)((char*)o2 + XS_BYTES)};

    // ws arenas (total ~203 MB): uT[2](->delT), zT[2](->ygT), ucT[2], wbf[2]
    const size_t SZ_DI = (size_t)NROW * DI * 2;       // 33.55 MB (256-aligned)
    const size_t SZ_WB = ((size_t)WB_TOT * 2 + 255) & ~(size_t)255;
    char* p = (char*)d_ws;
    ushort_t* uT[2]  = {(ushort_t*)p, (ushort_t*)(p + SZ_DI)};            p += 2 * SZ_DI;
    ushort_t* zT[2]  = {(ushort_t*)p, (ushort_t*)(p + SZ_DI)};            p += 2 * SZ_DI;
    ushort_t* ucT[2] = {(ushort_t*)p, (ushort_t*)(p + SZ_DI)};            p += 2 * SZ_DI;
    ushort_t* wbf[2] = {(ushort_t*)p, (ushort_t*)(p + SZ_WB)};
    ushort_t* delT[2] = {uT[0], uT[1]};   // uT dead after conv
    ushort_t* ygT[2]  = {zT[0], zT[1]};   // scan writes gated y over zT (read-before-write)

    ln_swap_kernel<<<NROW, 256, 0, stream>>>(x1, x2, ratio, ln1w, ln1b, ln2w, ln2b, xs[0], xs[1]);

    cvtw_kernel<<<dim3(WB_TOT / 256, 1, 2), 256, 0, stream>>>(
        inw[0], inw[1], xprw[0], xprw[1], outw[0], outw[1], wbf[0], wbf[1]);

    gemm_in_kernel<<<dim3(NROW / 128, 8, 2), 256, 0, stream>>>(
        xs[0], xs[1], wbf[0], wbf[1], uT[0], uT[1], zT[0], zT[1]);

    conv_silu_kernel<<<dim3((DI * NCHUNK) / 256, 1, 2), 256, 0, stream>>>(
        uT[0], uT[1], convw[0], convw[1], convb[0], convb[1], ucT[0], ucT[1]);

    gemm_xp_kernel<<<dim3(NROW / 128, 1, 2), 256, 0, stream>>>(
        ucT[0], ucT[1], wbf[0], wbf[1], dbl[0], dbl[1]);

    delta_kernel<<<dim3(128 * 128, 1, 2), 256, 0, stream>>>(
        dbl[0], dbl[1], dtw[0], dtw[1], dtb[0], dtb[1], delT[0], delT[1]);

    scan_kernel<<<dim3(BATCH * 32, 1, 2), 256, 0, stream>>>(
        delT[0], delT[1], ucT[0], ucT[1], dbl[0], dbl[1], zT[0], zT[1],
        alog[0], alog[1], Dp[0], Dp[1], ygT[0], ygT[1]);

    gemm_out_kernel<<<dim3(NROW / 128, 2, 2), 256, 0, stream>>>(
        ygT[0], ygT[1], wbf[0], wbf[1], x1, x2, o1, o2);
}

// Round 6
// 867.011 us; speedup vs baseline: 2.5535x; 1.2658x over previous
//
#include <hip/hip_runtime.h>

typedef unsigned short ushort_t;
typedef __attribute__((ext_vector_type(8))) short bh8;
typedef __attribute__((ext_vector_type(4))) float f32x4;
typedef __attribute__((ext_vector_type(2))) unsigned int u32x2;
typedef __attribute__((ext_vector_type(4))) unsigned int u32x4;

#define DIM 256
#define DI 512
#define LEN 2048
#define BATCH 16
#define NROW (BATCH * LEN)   // 32768
#define NCHUNK (NROW / 8)

__device__ __forceinline__ float b2f(ushort_t u) {
    union { unsigned int i; float f; } v; v.i = ((unsigned int)u) << 16; return v.f;
}
__device__ __forceinline__ ushort_t f2b(float f) {
    union { float ff; unsigned int i; } v; v.ff = f;
    unsigned int x = v.i;
    x += 0x7fffu + ((x >> 16) & 1u);
    return (ushort_t)(x >> 16);
}
// raw transcendentals (1 instr each; no libm edge-handling)
__device__ __forceinline__ float fexp2(float x) { float r; asm("v_exp_f32 %0, %1" : "=v"(r) : "v"(x)); return r; }
__device__ __forceinline__ float flog2(float x) { float r; asm("v_log_f32 %0, %1" : "=v"(r) : "v"(x)); return r; }
__device__ __forceinline__ float frcp (float x) { float r; asm("v_rcp_f32 %0, %1" : "=v"(r) : "v"(x)); return r; }
// pack 2 f32 -> 2 bf16 (RNE), 1 instr
__device__ __forceinline__ unsigned int cvtpk(float lo, float hi) {
    unsigned int r; asm("v_cvt_pk_bf16_f32 %0, %1, %2" : "=v"(r) : "v"(lo), "v"(hi)); return r;
}
// silu without f32 division: x * rcp(1 + exp2(-log2e * x))
__device__ __forceinline__ float silu(float x) {
    return x * frcp(1.0f + fexp2(-1.44269504f * x));
}
// 16-lane butterfly sum, 4 single-instr DPP adds; all lanes end with the sum
__device__ __forceinline__ float bsum16(float v) {
    float t;
    asm("v_add_f32_dpp %0, %1, %1 quad_perm:[1,0,3,2] row_mask:0xf bank_mask:0xf" : "=v"(t) : "v"(v));
    asm("v_add_f32_dpp %0, %1, %1 quad_perm:[2,3,0,1] row_mask:0xf bank_mask:0xf" : "=v"(v) : "v"(t));
    asm("v_add_f32_dpp %0, %1, %1 row_half_mirror row_mask:0xf bank_mask:0xf" : "=v"(t) : "v"(v));
    asm("v_add_f32_dpp %0, %1, %1 row_mirror row_mask:0xf bank_mask:0xf" : "=v"(v) : "v"(t));
    return v;
}
__device__ __forceinline__ void gload16(const ushort_t* g, ushort_t* l) {
    __builtin_amdgcn_global_load_lds((const __attribute__((address_space(1))) unsigned int*)g,
                                     (__attribute__((address_space(3))) unsigned int*)l, 16, 0, 0);
}

// ---------------- LayerNorm + channel swap (fp32 in -> bf16 out) ----------------
__global__ __launch_bounds__(256) void ln_swap_kernel(
    const float* __restrict__ x1, const float* __restrict__ x2,
    const float* __restrict__ ratio,
    const float* __restrict__ ln1w, const float* __restrict__ ln1b,
    const float* __restrict__ ln2w, const float* __restrict__ ln2b,
    ushort_t* __restrict__ xs1, ushort_t* __restrict__ xs2) {
    const int m = blockIdx.x;
    const int c = threadIdx.x;
    const size_t off = (size_t)m * DIM + c;
    float v1 = x1[off];
    float v2 = x2[off];
    float s1 = v1, q1 = v1 * v1, s2 = v2, q2 = v2 * v2;
    #pragma unroll
    for (int o = 32; o; o >>= 1) {
        s1 += __shfl_xor(s1, o); q1 += __shfl_xor(q1, o);
        s2 += __shfl_xor(s2, o); q2 += __shfl_xor(q2, o);
    }
    __shared__ float red[4][4];
    const int w = threadIdx.x >> 6;
    if ((threadIdx.x & 63) == 0) { red[w][0] = s1; red[w][1] = q1; red[w][2] = s2; red[w][3] = q2; }
    __syncthreads();
    s1 = red[0][0] + red[1][0] + red[2][0] + red[3][0];
    q1 = red[0][1] + red[1][1] + red[2][1] + red[3][1];
    s2 = red[0][2] + red[1][2] + red[2][2] + red[3][2];
    q2 = red[0][3] + red[1][3] + red[2][3] + red[3][3];
    const float inv = 1.0f / DIM;
    float mu1 = s1 * inv, mu2 = s2 * inv;
    float r1 = rsqrtf(q1 * inv - mu1 * mu1 + 1e-5f);
    float r2 = rsqrtf(q2 * inv - mu2 * mu2 + 1e-5f);
    float n1 = (v1 - mu1) * r1 * ln1w[c] + ln1b[c];
    float n2 = (v2 - mu2) * r2 * ln2w[c] + ln2b[c];
    int nc = (int)(DIM / (1.0f + expf(-ratio[0])));   // = 159
    xs2[off] = f2b(n2);
    xs1[off] = f2b(c < nc ? n2 : n1);
}

// ---------------- convert weights fp32 -> bf16 (once per call) ----------------
#define WB_IN 0
#define WB_XP 262144
#define WB_OUT 286720
#define WB_TOT 417792
__global__ __launch_bounds__(256) void cvtw_kernel(
    const float* __restrict__ iw0, const float* __restrict__ iw1,
    const float* __restrict__ xw0, const float* __restrict__ xw1,
    const float* __restrict__ ow0, const float* __restrict__ ow1,
    ushort_t* __restrict__ o0, ushort_t* __restrict__ o1) {
    const int e = blockIdx.z;
    const float* iw = e ? iw1 : iw0;
    const float* xw = e ? xw1 : xw0;
    const float* ow = e ? ow1 : ow0;
    ushort_t* o = e ? o1 : o0;
    const int idx = blockIdx.x * 256 + threadIdx.x;
    if (idx < WB_XP) o[idx] = f2b(iw[idx]);
    else if (idx < WB_OUT) o[idx] = f2b(xw[idx - WB_XP]);
    else if (idx < WB_TOT) o[idx] = f2b(ow[idx - WB_OUT]);
}

// ---------------- in-proj GEMM: [u|z] = xs @ in_w^T ; outputs TRANSPOSED ----------------
__global__ __launch_bounds__(256) void gemm_in_kernel(
    const ushort_t* __restrict__ A0, const ushort_t* __restrict__ A1,
    const ushort_t* __restrict__ Wb0, const ushort_t* __restrict__ Wb1,
    ushort_t* __restrict__ uT0, ushort_t* __restrict__ uT1,
    ushort_t* __restrict__ zT0, ushort_t* __restrict__ zT1) {
    const int e = blockIdx.z;
    const ushort_t* __restrict__ A = e ? A1 : A0;
    const ushort_t* __restrict__ W = e ? Wb1 : Wb0;
    ushort_t* __restrict__ uT = e ? uT1 : uT0;
    ushort_t* __restrict__ zT = e ? zT1 : zT0;
    const int m0 = blockIdx.x * 128;
    const int n0 = blockIdx.y * 128;
    const int tid = threadIdx.x, lane = tid & 63, wv = tid >> 6;
    const int wr = wv >> 1, wc = wv & 1;

    __shared__ ushort_t sA[128 * 32];
    __shared__ ushort_t sW[128 * 32];

    f32x4 acc[4][4];
    #pragma unroll
    for (int i = 0; i < 4; i++)
        #pragma unroll
        for (int j = 0; j < 4; j++) acc[i][j] = (f32x4){0.f, 0.f, 0.f, 0.f};

    const ushort_t* Ap = A + (size_t)(m0 + wv * 32 + (lane >> 2)) * 256 + (lane & 3) * 8;
    const ushort_t* Wp = W + (size_t)(n0 + wv * 32 + (lane >> 2)) * 256 + (lane & 3) * 8;

    for (int kt = 0; kt < 256; kt += 32) {
        __syncthreads();
        gload16(Ap + kt,             &sA[(wv * 32) * 32]);
        gload16(Ap + kt + 16 * 256,  &sA[(wv * 32 + 16) * 32]);
        gload16(Wp + kt,             &sW[(wv * 32) * 32]);
        gload16(Wp + kt + 16 * 256,  &sW[(wv * 32 + 16) * 32]);
        __syncthreads();
        bh8 af[4], wf[4];
        #pragma unroll
        for (int i = 0; i < 4; i++)
            af[i] = *(const bh8*)(&sA[(wr * 64 + i * 16 + (lane & 15)) * 32 + (lane >> 4) * 8]);
        #pragma unroll
        for (int j = 0; j < 4; j++)
            wf[j] = *(const bh8*)(&sW[(wc * 64 + j * 16 + (lane & 15)) * 32 + (lane >> 4) * 8]);
        #pragma unroll
        for (int i = 0; i < 4; i++)
            #pragma unroll
            for (int j = 0; j < 4; j++)
                acc[i][j] = __builtin_amdgcn_mfma_f32_16x16x32_bf16(af[i], wf[j], acc[i][j], 0, 0, 0);
    }

    #pragma unroll
    for (int i = 0; i < 4; i++) {
        #pragma unroll
        for (int j = 0; j < 4; j++) {
            const int rbase = m0 + wr * 64 + i * 16 + (lane >> 4) * 4;
            const int col = n0 + wc * 64 + j * 16 + (lane & 15);
            u32x2 vv;
            vv[0] = cvtpk(acc[i][j][0], acc[i][j][1]);
            vv[1] = cvtpk(acc[i][j][2], acc[i][j][3]);
            if (col < DI) *(u32x2*)(&uT[(size_t)col * NROW + rbase]) = vv;
            else          *(u32x2*)(&zT[(size_t)(col - DI) * NROW + rbase]) = vv;
        }
    }
}

// ---------------- causal depthwise conv4 + SiLU, time-major ----------------
__global__ __launch_bounds__(256) void conv_silu_kernel(
    const ushort_t* __restrict__ uT0, const ushort_t* __restrict__ uT1,
    const float* __restrict__ cw0, const float* __restrict__ cw1,
    const float* __restrict__ cb0, const float* __restrict__ cb1,
    ushort_t* __restrict__ ucT0, ushort_t* __restrict__ ucT1) {
    const int e = blockIdx.z;
    const ushort_t* __restrict__ uT = e ? uT1 : uT0;
    const float* __restrict__ cw = e ? cw1 : cw0;
    const float* __restrict__ cb = e ? cb1 : cb0;
    ushort_t* __restrict__ ucT = e ? ucT1 : ucT0;

    const int g = blockIdx.x * 256 + threadIdx.x;
    const int c = g & (NCHUNK - 1);
    const int d = g >> 12;
    const int b = c >> 8;
    const int t0 = (c & 255) * 8;
    const size_t base = (size_t)d * NROW + b * LEN + t0;

    bh8 cur = *(const bh8*)(uT + base);
    float win[11];
    if (t0) {
        win[0] = b2f(uT[base - 3]); win[1] = b2f(uT[base - 2]); win[2] = b2f(uT[base - 1]);
    } else {
        win[0] = 0.f; win[1] = 0.f; win[2] = 0.f;
    }
    #pragma unroll
    for (int j = 0; j < 8; j++) win[3 + j] = b2f((ushort_t)cur[j]);
    const f32x4 w = *(const f32x4*)(cw + d * 4);
    const float bias = cb[d];
    float s[8];
    #pragma unroll
    for (int j = 0; j < 8; j++) {
        const float a = bias + w[0] * win[j] + w[1] * win[j + 1] + w[2] * win[j + 2] + w[3] * win[j + 3];
        s[j] = silu(a);
    }
    u32x4 o;
    #pragma unroll
    for (int k = 0; k < 4; k++) o[k] = cvtpk(s[2 * k], s[2 * k + 1]);
    *(u32x4*)(ucT + base) = o;
}

// ---------------- x-proj GEMM: dblT[n][m] = xprw @ ucT (n<48) ----------------
__global__ __launch_bounds__(256) void gemm_xp_kernel(
    const ushort_t* __restrict__ ucT0, const ushort_t* __restrict__ ucT1,
    const ushort_t* __restrict__ Wb0, const ushort_t* __restrict__ Wb1,
    float* __restrict__ dbl0, float* __restrict__ dbl1) {
    const int e = blockIdx.z;
    const ushort_t* __restrict__ ucT = e ? ucT1 : ucT0;
    const ushort_t* __restrict__ W = (e ? Wb1 : Wb0) + WB_XP;
    float* __restrict__ dbl = e ? dbl1 : dbl0;
    const int m0 = blockIdx.x * 128;
    const int tid = threadIdx.x, lane = tid & 63;
    const int wc = tid >> 6;

    __shared__ ushort_t sW[48 * 40];
    __shared__ ushort_t sB[128 * 40];

    f32x4 acc[3][2];
    #pragma unroll
    for (int i = 0; i < 3; i++)
        #pragma unroll
        for (int j = 0; j < 2; j++) acc[i][j] = (f32x4){0.f, 0.f, 0.f, 0.f};

    const int kk = tid >> 3, mc = (tid & 7) * 16;
    const ushort_t* Bp = ucT + (size_t)kk * NROW + m0 + mc;

    for (int kt = 0; kt < 512; kt += 32) {
        __syncthreads();
        if (tid < 192) {
            const int r = tid >> 2, cc = (tid & 3) * 8;
            bh8 v = *(const bh8*)(W + (size_t)r * 512 + kt + cc);
            *(bh8*)(&sW[r * 40 + cc]) = v;
        }
        bh8 a0 = *(const bh8*)(Bp + (size_t)kt * NROW);
        bh8 a1 = *(const bh8*)(Bp + (size_t)kt * NROW + 8);
        #pragma unroll
        for (int q = 0; q < 8; q++) {
            sB[(mc + q) * 40 + kk] = (ushort_t)a0[q];
            sB[(mc + 8 + q) * 40 + kk] = (ushort_t)a1[q];
        }
        __syncthreads();
        bh8 af[3], wf[2];
        #pragma unroll
        for (int i = 0; i < 3; i++)
            af[i] = *(const bh8*)(&sW[(i * 16 + (lane & 15)) * 40 + (lane >> 4) * 8]);
        #pragma unroll
        for (int j = 0; j < 2; j++)
            wf[j] = *(const bh8*)(&sB[(wc * 32 + j * 16 + (lane & 15)) * 40 + (lane >> 4) * 8]);
        #pragma unroll
        for (int i = 0; i < 3; i++)
            #pragma unroll
            for (int j = 0; j < 2; j++)
                acc[i][j] = __builtin_amdgcn_mfma_f32_16x16x32_bf16(af[i], wf[j], acc[i][j], 0, 0, 0);
    }

    #pragma unroll
    for (int i = 0; i < 3; i++) {
        #pragma unroll
        for (int j = 0; j < 2; j++) {
            const int nb = i * 16 + (lane >> 4) * 4;
            const int mm = m0 + wc * 32 + j * 16 + (lane & 15);
            #pragma unroll
            for (int r = 0; r < 4; r++)
                dbl[(size_t)(nb + r) * NROW + mm] = acc[i][j][r];
        }
    }
}

// ---------------- delta = softplus(dt @ dt_w^T + dt_b), transposed I/O ----------------
__global__ __launch_bounds__(256) void delta_kernel(
    const float* __restrict__ dblT0, const float* __restrict__ dblT1,
    const float* __restrict__ dtw0, const float* __restrict__ dtw1,
    const float* __restrict__ dtb0, const float* __restrict__ dtb1,
    ushort_t* __restrict__ delT0, ushort_t* __restrict__ delT1) {
    const int e = blockIdx.z;
    const float* __restrict__ dblT = e ? dblT1 : dblT0;
    const float* __restrict__ dtw = e ? dtw1 : dtw0;
    const float* __restrict__ dtb = e ? dtb1 : dtb0;
    ushort_t* __restrict__ delT = e ? delT1 : delT0;

    const int tid = threadIdx.x, lane = tid & 63, wv = tid >> 6;
    const int bx = blockIdx.x;
    const int d = (bx & 127) * 4 + wv;
    const int m0 = (bx >> 7) * 256 + lane * 4;

    const float bias = dtb[d];
    f32x4 acc = {bias, bias, bias, bias};
    #pragma unroll
    for (int k = 0; k < 16; k++) {
        const float wk = dtw[d * 16 + k];
        const f32x4 bv = *(const f32x4*)(dblT + (size_t)k * NROW + m0);
        #pragma unroll
        for (int c = 0; c < 4; c++) acc[c] = fmaf(wk, bv[c], acc[c]);
    }
    float sp[4];
    #pragma unroll
    for (int c = 0; c < 4; c++) {
        const float x = acc[c];
        // softplus = ln2 * log2(1 + exp2(x*log2e)); exact enough, div/libm-free
        sp[c] = (x > 20.0f) ? x : 0.69314718f * flog2(1.0f + fexp2(1.44269504f * x));
    }
    u32x2 r;
    r[0] = cvtpk(sp[0], sp[1]);
    r[1] = cvtpk(sp[2], sp[3]);
    *(u32x2*)(&delT[(size_t)d * NROW + m0]) = r;
}

// ---------------- selective scan (no gate): yT = y_scan + u*Dp, time-major ----------------
// yT aliases delT (write of block t strictly after all reads <= t+8 issued).
__global__ __launch_bounds__(256) void scan_kernel(
    const ushort_t* delT0, const ushort_t* delT1,                 // alias yT: no restrict
    const ushort_t* __restrict__ ucT0, const ushort_t* __restrict__ ucT1,
    const float* __restrict__ dblT0, const float* __restrict__ dblT1,
    const float* __restrict__ al0, const float* __restrict__ al1,
    const float* __restrict__ Dp0, const float* __restrict__ Dp1,
    ushort_t* y0, ushort_t* y1) {
    const int e = blockIdx.z;
    const ushort_t* delT = e ? delT1 : delT0;
    const ushort_t* __restrict__ ucT  = e ? ucT1 : ucT0;
    const float* __restrict__ dbl     = e ? dblT1 : dblT0;
    const float* __restrict__ al      = e ? al1 : al0;
    const float* __restrict__ Dq      = e ? Dp1 : Dp0;
    ushort_t* yo                      = e ? y1 : y0;

    const int b = blockIdx.x >> 5;
    const int dtile = blockIdx.x & 31;
    const int tid = threadIdx.x;
    const int s = tid & 15;
    const int d = dtile * 16 + (tid >> 4);

    const float A2 = -expf(al[(d << 4) + s]) * 1.44269504f;
    const float Dpv = Dq[d];

    const ushort_t* dT = delT + (size_t)d * NROW + b * LEN;
    const ushort_t* uT = ucT + (size_t)d * NROW + b * LEN;
    const float* Bp = dbl + (size_t)(16 + s) * NROW + b * LEN;
    const float* Cp = dbl + (size_t)(32 + s) * NROW + b * LEN;
    ushort_t* yp = yo + (size_t)d * NROW + b * LEN;
    const bool writer = (s == 0);

    float h = 0.f;
    bh8 dv = *(const bh8*)dT;
    bh8 uv = *(const bh8*)uT;
    f32x4 B0 = *(const f32x4*)Bp, B1 = *(const f32x4*)(Bp + 4);
    f32x4 C0 = *(const f32x4*)Cp, C1 = *(const f32x4*)(Cp + 4);

    for (int t0 = 0; t0 < LEN; t0 += 8) {
        // unconditional prefetch: last-iter reads land in adjacent arenas (allocated, unused)
        bh8 dn = *(const bh8*)(dT + t0 + 8);
        bh8 un = *(const bh8*)(uT + t0 + 8);
        f32x4 Bn0 = *(const f32x4*)(Bp + t0 + 8), Bn1 = *(const f32x4*)(Bp + t0 + 12);
        f32x4 Cn0 = *(const f32x4*)(Cp + t0 + 8), Cn1 = *(const f32x4*)(Cp + t0 + 12);
        float yv[8], uf[8];
        #pragma unroll
        for (int j = 0; j < 8; j++) {
            const float dt = b2f((ushort_t)dv[j]);
            uf[j] = b2f((ushort_t)uv[j]);
            const float Bj = (j < 4) ? B0[j] : B1[j - 4];
            const float Cj = (j < 4) ? C0[j] : C1[j - 4];
            h = fmaf(h, fexp2(dt * A2), dt * uf[j] * Bj);
            yv[j] = h * Cj;
        }
        #pragma unroll
        for (int j = 0; j < 8; j++) yv[j] = bsum16(yv[j]);
        u32x4 o;
        #pragma unroll
        for (int k = 0; k < 4; k++)
            o[k] = cvtpk(fmaf(uf[2 * k], Dpv, yv[2 * k]), fmaf(uf[2 * k + 1], Dpv, yv[2 * k + 1]));
        if (writer) *(u32x4*)(yp + t0) = o;   // overwrites delT[t0..t0+7] after consumption
        dv = dn; uv = un; B0 = Bn0; B1 = Bn1; C0 = Cn0; C1 = Cn1;
    }
}

// ---------------- gate: ygT = yT * silu(zT), elementwise, in-place over zT ----------------
__global__ __launch_bounds__(256) void gate_kernel(
    const ushort_t* __restrict__ yT0, const ushort_t* __restrict__ yT1,
    ushort_t* zg0, ushort_t* zg1) {
    const int e = blockIdx.z;
    const ushort_t* __restrict__ yv = e ? yT1 : yT0;
    ushort_t* zg = e ? zg1 : zg0;
    const size_t i8 = ((size_t)blockIdx.x * 256 + threadIdx.x) * 8;
    bh8 y8 = *(const bh8*)(yv + i8);
    bh8 z8 = *(const bh8*)(zg + i8);
    float p[8];
    #pragma unroll
    for (int j = 0; j < 8; j++)
        p[j] = b2f((ushort_t)y8[j]) * silu(b2f((ushort_t)z8[j]));
    u32x4 o;
    #pragma unroll
    for (int k = 0; k < 4; k++) o[k] = cvtpk(p[2 * k], p[2 * k + 1]);
    *(u32x4*)(zg + i8) = o;
}

// ---------------- out-proj GEMM: o = yg @ out_w^T + residual (fp32) ----------------
__global__ __launch_bounds__(256) void gemm_out_kernel(
    const ushort_t* __restrict__ ygT0, const ushort_t* __restrict__ ygT1,
    const ushort_t* __restrict__ Wb0, const ushort_t* __restrict__ Wb1,
    const float* __restrict__ r0, const float* __restrict__ r1,
    float* __restrict__ o0, float* __restrict__ o1) {
    const int e = blockIdx.z;
    const ushort_t* __restrict__ ygT = e ? ygT1 : ygT0;
    const ushort_t* __restrict__ W = (e ? Wb1 : Wb0) + WB_OUT;
    const float* __restrict__ rr = e ? r1 : r0;
    float* __restrict__ oo = e ? o1 : o0;
    const int m0 = blockIdx.x * 128;
    const int n0 = blockIdx.y * 128;
    const int tid = threadIdx.x, lane = tid & 63, wv = tid >> 6;
    const int wr = wv >> 1, wc = wv & 1;

    __shared__ ushort_t sA[128 * 40];
    __shared__ ushort_t sW[128 * 32];

    f32x4 acc[4][4];
    #pragma unroll
    for (int i = 0; i < 4; i++)
        #pragma unroll
        for (int j = 0; j < 4; j++) acc[i][j] = (f32x4){0.f, 0.f, 0.f, 0.f};

    const int kk = tid >> 3, mc = (tid & 7) * 16;
    const ushort_t* Yp = ygT + (size_t)kk * NROW + m0 + mc;
    const ushort_t* Wp = W + (size_t)(n0 + wv * 32 + (lane >> 2)) * 512 + (lane & 3) * 8;

    for (int kt = 0; kt < 512; kt += 32) {
        __syncthreads();
        gload16(Wp + kt,             &sW[(wv * 32) * 32]);
        gload16(Wp + kt + 16 * 512,  &sW[(wv * 32 + 16) * 32]);
        bh8 a0 = *(const bh8*)(Yp + (size_t)kt * NROW);
        bh8 a1 = *(const bh8*)(Yp + (size_t)kt * NROW + 8);
        #pragma unroll
        for (int q = 0; q < 8; q++) {
            sA[(mc + q) * 40 + kk] = (ushort_t)a0[q];
            sA[(mc + 8 + q) * 40 + kk] = (ushort_t)a1[q];
        }
        __syncthreads();
        bh8 af[4], wf[4];
        #pragma unroll
        for (int i = 0; i < 4; i++)
            af[i] = *(const bh8*)(&sA[(wr * 64 + i * 16 + (lane & 15)) * 40 + (lane >> 4) * 8]);
        #pragma unroll
        for (int j = 0; j < 4; j++)
            wf[j] = *(const bh8*)(&sW[(wc * 64 + j * 16 + (lane & 15)) * 32 + (lane >> 4) * 8]);
        #pragma unroll
        for (int i = 0; i < 4; i++)
            #pragma unroll
            for (int j = 0; j < 4; j++)
                acc[i][j] = __builtin_amdgcn_mfma_f32_16x16x32_bf16(af[i], wf[j], acc[i][j], 0, 0, 0);
    }

    #pragma unroll
    for (int i = 0; i < 4; i++) {
        #pragma unroll
        for (int j = 0; j < 4; j++) {
            const int rbase = m0 + wr * 64 + i * 16 + (lane >> 4) * 4;
            const int col = n0 + wc * 64 + j * 16 + (lane & 15);
            #pragma unroll
            for (int r = 0; r < 4; r++) {
                const size_t off = (size_t)(rbase + r) * DIM + col;
                oo[off] = acc[i][j][r] + rr[off];
            }
        }
    }
}

extern "C" void kernel_launch(void* const* d_in, const int* in_sizes, int n_in,
                              void* d_out, int out_size, void* d_ws, size_t ws_size,
                              hipStream_t stream) {
    const float* x1    = (const float*)d_in[0];
    const float* x2    = (const float*)d_in[1];
    const float* ratio = (const float*)d_in[2];
    const float* ln1w  = (const float*)d_in[3];
    const float* ln1b  = (const float*)d_in[4];
    const float* ln2w  = (const float*)d_in[5];
    const float* ln2b  = (const float*)d_in[6];
    const float* inw[2]   = {(const float*)d_in[7],  (const float*)d_in[16]};
    const float* convw[2] = {(const float*)d_in[8],  (const float*)d_in[17]};
    const float* convb[2] = {(const float*)d_in[9],  (const float*)d_in[18]};
    const float* xprw[2]  = {(const float*)d_in[10], (const float*)d_in[19]};
    const float* dtw[2]   = {(const float*)d_in[11], (const float*)d_in[20]};
    const float* dtb[2]   = {(const float*)d_in[12], (const float*)d_in[21]};
    const float* alog[2]  = {(const float*)d_in[13], (const float*)d_in[22]};
    const float* Dp[2]    = {(const float*)d_in[14], (const float*)d_in[23]};
    const float* outw[2]  = {(const float*)d_in[15], (const float*)d_in[24]};

    // d_out map (fp32 o1 | o2): xs[e] bf16 @ bytes [0,16.78M) of each half;
    // dbl[e] f32 @ [16.78M, 23.07M). All dead before out-proj writes.
    float* o1 = (float*)d_out;
    float* o2 = o1 + (size_t)NROW * DIM;
    ushort_t* xs[2] = {(ushort_t*)o1, (ushort_t*)o2};
    const size_t XS_BYTES = (size_t)NROW * DIM * 2;
    float* dbl[2] = {(float*)((char*)o1 + XS_BYTES), (float*)((char*)o2 + XS_BYTES)};

    // ws arenas (~203 MB): uT[2] (-> delT -> yT), zT[2] (-> ygT), ucT[2], wbf[2]
    const size_t SZ_DI = (size_t)NROW * DI * 2;
    const size_t SZ_WB = ((size_t)WB_TOT * 2 + 255) & ~(size_t)255;
    char* p = (char*)d_ws;
    ushort_t* uT[2]  = {(ushort_t*)p, (ushort_t*)(p + SZ_DI)};            p += 2 * SZ_DI;
    ushort_t* zT[2]  = {(ushort_t*)p, (ushort_t*)(p + SZ_DI)};            p += 2 * SZ_DI;
    ushort_t* ucT[2] = {(ushort_t*)p, (ushort_t*)(p + SZ_DI)};            p += 2 * SZ_DI;
    ushort_t* wbf[2] = {(ushort_t*)p, (ushort_t*)(p + SZ_WB)};
    ushort_t* delT[2] = {uT[0], uT[1]};   // uT dead after conv
    ushort_t* yT[2]   = {uT[0], uT[1]};   // scan writes yT over delT
    ushort_t* ygT[2]  = {zT[0], zT[1]};   // gate writes yg over zT

    ln_swap_kernel<<<NROW, 256, 0, stream>>>(x1, x2, ratio, ln1w, ln1b, ln2w, ln2b, xs[0], xs[1]);

    cvtw_kernel<<<dim3(WB_TOT / 256, 1, 2), 256, 0, stream>>>(
        inw[0], inw[1], xprw[0], xprw[1], outw[0], outw[1], wbf[0], wbf[1]);

    gemm_in_kernel<<<dim3(NROW / 128, 8, 2), 256, 0, stream>>>(
        xs[0], xs[1], wbf[0], wbf[1], uT[0], uT[1], zT[0], zT[1]);

    conv_silu_kernel<<<dim3((DI * NCHUNK) / 256, 1, 2), 256, 0, stream>>>(
        uT[0], uT[1], convw[0], convw[1], convb[0], convb[1], ucT[0], ucT[1]);

    gemm_xp_kernel<<<dim3(NROW / 128, 1, 2), 256, 0, stream>>>(
        ucT[0], ucT[1], wbf[0], wbf[1], dbl[0], dbl[1]);

    delta_kernel<<<dim3(128 * 128, 1, 2), 256, 0, stream>>>(
        dbl[0], dbl[1], dtw[0], dtw[1], dtb[0], dtb[1], delT[0], delT[1]);

    scan_kernel<<<dim3(BATCH * 32, 1, 2), 256, 0, stream>>>(
        delT[0], delT[1], ucT[0], ucT[1], dbl[0], dbl[1],
        alog[0], alog[1], Dp[0], Dp[1], yT[0], yT[1]);

    gate_kernel<<<dim3((NROW * DI / 8) / 256, 1, 2), 256, 0, stream>>>(
        yT[0], yT[1], ygT[0], ygT[1]);

    gemm_out_kernel<<<dim3(NROW / 128, 2, 2), 256, 0, stream>>>(
        ygT[0], ygT[1], wbf[0], wbf[1], x1, x2, o1, o2);
}

// Round 7
// 801.066 us; speedup vs baseline: 2.7637x; 1.0823x over previous
//
#include <hip/hip_runtime.h>

typedef unsigned short ushort_t;
typedef __attribute__((ext_vector_type(8))) short bh8;
typedef __attribute__((ext_vector_type(4))) float f32x4;
typedef __attribute__((ext_vector_type(2))) unsigned int u32x2;
typedef __attribute__((ext_vector_type(4))) unsigned int u32x4;

#define DIM 256
#define DI 512
#define LEN 2048
#define BATCH 16
#define NROW (BATCH * LEN)   // 32768
#define NCHUNK (NROW / 8)

__device__ __forceinline__ float b2f(ushort_t u) {
    union { unsigned int i; float f; } v; v.i = ((unsigned int)u) << 16; return v.f;
}
__device__ __forceinline__ ushort_t f2b(float f) {
    union { float ff; unsigned int i; } v; v.ff = f;
    unsigned int x = v.i;
    x += 0x7fffu + ((x >> 16) & 1u);
    return (ushort_t)(x >> 16);
}
// raw transcendentals (1 instr each; no libm edge-handling)
__device__ __forceinline__ float fexp2(float x) { float r; asm("v_exp_f32 %0, %1" : "=v"(r) : "v"(x)); return r; }
__device__ __forceinline__ float flog2(float x) { float r; asm("v_log_f32 %0, %1" : "=v"(r) : "v"(x)); return r; }
__device__ __forceinline__ float frcp (float x) { float r; asm("v_rcp_f32 %0, %1" : "=v"(r) : "v"(x)); return r; }
// pack 2 f32 -> 2 bf16 (RNE), 1 instr
__device__ __forceinline__ unsigned int cvtpk(float lo, float hi) {
    unsigned int r; asm("v_cvt_pk_bf16_f32 %0, %1, %2" : "=v"(r) : "v"(lo), "v"(hi)); return r;
}
// silu without f32 division: x * rcp(1 + exp2(-log2e * x))
__device__ __forceinline__ float silu(float x) {
    return x * frcp(1.0f + fexp2(-1.44269504f * x));
}
// 16-lane butterfly sum, 4 single-instr DPP adds; all lanes end with the sum
__device__ __forceinline__ float bsum16(float v) {
    float t;
    asm("v_add_f32_dpp %0, %1, %1 quad_perm:[1,0,3,2] row_mask:0xf bank_mask:0xf" : "=v"(t) : "v"(v));
    asm("v_add_f32_dpp %0, %1, %1 quad_perm:[2,3,0,1] row_mask:0xf bank_mask:0xf" : "=v"(v) : "v"(t));
    asm("v_add_f32_dpp %0, %1, %1 row_half_mirror row_mask:0xf bank_mask:0xf" : "=v"(t) : "v"(v));
    asm("v_add_f32_dpp %0, %1, %1 row_mirror row_mask:0xf bank_mask:0xf" : "=v"(v) : "v"(t));
    return v;
}
__device__ __forceinline__ void gload16(const ushort_t* g, ushort_t* l) {
    __builtin_amdgcn_global_load_lds((const __attribute__((address_space(1))) unsigned int*)g,
                                     (__attribute__((address_space(3))) unsigned int*)l, 16, 0, 0);
}

// ---------------- LayerNorm + channel swap (fp32 in -> bf16 out) ----------------
__global__ __launch_bounds__(256) void ln_swap_kernel(
    const float* __restrict__ x1, const float* __restrict__ x2,
    const float* __restrict__ ratio,
    const float* __restrict__ ln1w, const float* __restrict__ ln1b,
    const float* __restrict__ ln2w, const float* __restrict__ ln2b,
    ushort_t* __restrict__ xs1, ushort_t* __restrict__ xs2) {
    const int m = blockIdx.x;
    const int c = threadIdx.x;
    const size_t off = (size_t)m * DIM + c;
    float v1 = x1[off];
    float v2 = x2[off];
    float s1 = v1, q1 = v1 * v1, s2 = v2, q2 = v2 * v2;
    #pragma unroll
    for (int o = 32; o; o >>= 1) {
        s1 += __shfl_xor(s1, o); q1 += __shfl_xor(q1, o);
        s2 += __shfl_xor(s2, o); q2 += __shfl_xor(q2, o);
    }
    __shared__ float red[4][4];
    const int w = threadIdx.x >> 6;
    if ((threadIdx.x & 63) == 0) { red[w][0] = s1; red[w][1] = q1; red[w][2] = s2; red[w][3] = q2; }
    __syncthreads();
    s1 = red[0][0] + red[1][0] + red[2][0] + red[3][0];
    q1 = red[0][1] + red[1][1] + red[2][1] + red[3][1];
    s2 = red[0][2] + red[1][2] + red[2][2] + red[3][2];
    q2 = red[0][3] + red[1][3] + red[2][3] + red[3][3];
    const float inv = 1.0f / DIM;
    float mu1 = s1 * inv, mu2 = s2 * inv;
    float r1 = rsqrtf(q1 * inv - mu1 * mu1 + 1e-5f);
    float r2 = rsqrtf(q2 * inv - mu2 * mu2 + 1e-5f);
    float n1 = (v1 - mu1) * r1 * ln1w[c] + ln1b[c];
    float n2 = (v2 - mu2) * r2 * ln2w[c] + ln2b[c];
    int nc = (int)(DIM / (1.0f + expf(-ratio[0])));   // = 159
    xs2[off] = f2b(n2);
    xs1[off] = f2b(c < nc ? n2 : n1);
}

// ---------------- convert weights fp32 -> bf16 (once per call) ----------------
#define WB_IN 0
#define WB_XP 262144
#define WB_OUT 286720
#define WB_TOT 417792
__global__ __launch_bounds__(256) void cvtw_kernel(
    const float* __restrict__ iw0, const float* __restrict__ iw1,
    const float* __restrict__ xw0, const float* __restrict__ xw1,
    const float* __restrict__ ow0, const float* __restrict__ ow1,
    ushort_t* __restrict__ o0, ushort_t* __restrict__ o1) {
    const int e = blockIdx.z;
    const float* iw = e ? iw1 : iw0;
    const float* xw = e ? xw1 : xw0;
    const float* ow = e ? ow1 : ow0;
    ushort_t* o = e ? o1 : o0;
    const int idx = blockIdx.x * 256 + threadIdx.x;
    if (idx < WB_XP) o[idx] = f2b(iw[idx]);
    else if (idx < WB_OUT) o[idx] = f2b(xw[idx - WB_XP]);
    else if (idx < WB_TOT) o[idx] = f2b(ow[idx - WB_OUT]);
}

// ---------------- in-proj GEMM: [u|z] = xs @ in_w^T ; outputs TRANSPOSED ----------------
__global__ __launch_bounds__(256) void gemm_in_kernel(
    const ushort_t* __restrict__ A0, const ushort_t* __restrict__ A1,
    const ushort_t* __restrict__ Wb0, const ushort_t* __restrict__ Wb1,
    ushort_t* __restrict__ uT0, ushort_t* __restrict__ uT1,
    ushort_t* __restrict__ zT0, ushort_t* __restrict__ zT1) {
    const int e = blockIdx.z;
    const ushort_t* __restrict__ A = e ? A1 : A0;
    const ushort_t* __restrict__ W = e ? Wb1 : Wb0;
    ushort_t* __restrict__ uT = e ? uT1 : uT0;
    ushort_t* __restrict__ zT = e ? zT1 : zT0;
    const int m0 = blockIdx.x * 128;
    const int n0 = blockIdx.y * 128;
    const int tid = threadIdx.x, lane = tid & 63, wv = tid >> 6;
    const int wr = wv >> 1, wc = wv & 1;

    __shared__ ushort_t sA[128 * 32];
    __shared__ ushort_t sW[128 * 32];

    f32x4 acc[4][4];
    #pragma unroll
    for (int i = 0; i < 4; i++)
        #pragma unroll
        for (int j = 0; j < 4; j++) acc[i][j] = (f32x4){0.f, 0.f, 0.f, 0.f};

    const ushort_t* Ap = A + (size_t)(m0 + wv * 32 + (lane >> 2)) * 256 + (lane & 3) * 8;
    const ushort_t* Wp = W + (size_t)(n0 + wv * 32 + (lane >> 2)) * 256 + (lane & 3) * 8;

    for (int kt = 0; kt < 256; kt += 32) {
        __syncthreads();
        gload16(Ap + kt,             &sA[(wv * 32) * 32]);
        gload16(Ap + kt + 16 * 256,  &sA[(wv * 32 + 16) * 32]);
        gload16(Wp + kt,             &sW[(wv * 32) * 32]);
        gload16(Wp + kt + 16 * 256,  &sW[(wv * 32 + 16) * 32]);
        __syncthreads();
        bh8 af[4], wf[4];
        #pragma unroll
        for (int i = 0; i < 4; i++)
            af[i] = *(const bh8*)(&sA[(wr * 64 + i * 16 + (lane & 15)) * 32 + (lane >> 4) * 8]);
        #pragma unroll
        for (int j = 0; j < 4; j++)
            wf[j] = *(const bh8*)(&sW[(wc * 64 + j * 16 + (lane & 15)) * 32 + (lane >> 4) * 8]);
        #pragma unroll
        for (int i = 0; i < 4; i++)
            #pragma unroll
            for (int j = 0; j < 4; j++)
                acc[i][j] = __builtin_amdgcn_mfma_f32_16x16x32_bf16(af[i], wf[j], acc[i][j], 0, 0, 0);
    }

    #pragma unroll
    for (int i = 0; i < 4; i++) {
        #pragma unroll
        for (int j = 0; j < 4; j++) {
            const int rbase = m0 + wr * 64 + i * 16 + (lane >> 4) * 4;
            const int col = n0 + wc * 64 + j * 16 + (lane & 15);
            u32x2 vv;
            vv[0] = cvtpk(acc[i][j][0], acc[i][j][1]);
            vv[1] = cvtpk(acc[i][j][2], acc[i][j][3]);
            if (col < DI) *(u32x2*)(&uT[(size_t)col * NROW + rbase]) = vv;
            else          *(u32x2*)(&zT[(size_t)(col - DI) * NROW + rbase]) = vv;
        }
    }
}

// ---------------- causal depthwise conv4 + SiLU, time-major ----------------
__global__ __launch_bounds__(256) void conv_silu_kernel(
    const ushort_t* __restrict__ uT0, const ushort_t* __restrict__ uT1,
    const float* __restrict__ cw0, const float* __restrict__ cw1,
    const float* __restrict__ cb0, const float* __restrict__ cb1,
    ushort_t* __restrict__ ucT0, ushort_t* __restrict__ ucT1) {
    const int e = blockIdx.z;
    const ushort_t* __restrict__ uT = e ? uT1 : uT0;
    const float* __restrict__ cw = e ? cw1 : cw0;
    const float* __restrict__ cb = e ? cb1 : cb0;
    ushort_t* __restrict__ ucT = e ? ucT1 : ucT0;

    const int g = blockIdx.x * 256 + threadIdx.x;
    const int c = g & (NCHUNK - 1);
    const int d = g >> 12;
    const int b = c >> 8;
    const int t0 = (c & 255) * 8;
    const size_t base = (size_t)d * NROW + b * LEN + t0;

    bh8 cur = *(const bh8*)(uT + base);
    float win[11];
    if (t0) {
        win[0] = b2f(uT[base - 3]); win[1] = b2f(uT[base - 2]); win[2] = b2f(uT[base - 1]);
    } else {
        win[0] = 0.f; win[1] = 0.f; win[2] = 0.f;
    }
    #pragma unroll
    for (int j = 0; j < 8; j++) win[3 + j] = b2f((ushort_t)cur[j]);
    const f32x4 w = *(const f32x4*)(cw + d * 4);
    const float bias = cb[d];
    float s[8];
    #pragma unroll
    for (int j = 0; j < 8; j++) {
        const float a = bias + w[0] * win[j] + w[1] * win[j + 1] + w[2] * win[j + 2] + w[3] * win[j + 3];
        s[j] = silu(a);
    }
    u32x4 o;
    #pragma unroll
    for (int k = 0; k < 4; k++) o[k] = cvtpk(s[2 * k], s[2 * k + 1]);
    *(u32x4*)(ucT + base) = o;
}

// ---------------- x-proj GEMM: dblT[n][m] = xprw @ ucT (n<48) ----------------
__global__ __launch_bounds__(256) void gemm_xp_kernel(
    const ushort_t* __restrict__ ucT0, const ushort_t* __restrict__ ucT1,
    const ushort_t* __restrict__ Wb0, const ushort_t* __restrict__ Wb1,
    float* __restrict__ dbl0, float* __restrict__ dbl1) {
    const int e = blockIdx.z;
    const ushort_t* __restrict__ ucT = e ? ucT1 : ucT0;
    const ushort_t* __restrict__ W = (e ? Wb1 : Wb0) + WB_XP;
    float* __restrict__ dbl = e ? dbl1 : dbl0;
    const int m0 = blockIdx.x * 128;
    const int tid = threadIdx.x, lane = tid & 63;
    const int wc = tid >> 6;

    __shared__ ushort_t sW[48 * 40];
    __shared__ ushort_t sB[128 * 40];

    f32x4 acc[3][2];
    #pragma unroll
    for (int i = 0; i < 3; i++)
        #pragma unroll
        for (int j = 0; j < 2; j++) acc[i][j] = (f32x4){0.f, 0.f, 0.f, 0.f};

    const int kk = tid >> 3, mc = (tid & 7) * 16;
    const ushort_t* Bp = ucT + (size_t)kk * NROW + m0 + mc;

    for (int kt = 0; kt < 512; kt += 32) {
        __syncthreads();
        if (tid < 192) {
            const int r = tid >> 2, cc = (tid & 3) * 8;
            bh8 v = *(const bh8*)(W + (size_t)r * 512 + kt + cc);
            *(bh8*)(&sW[r * 40 + cc]) = v;
        }
        bh8 a0 = *(const bh8*)(Bp + (size_t)kt * NROW);
        bh8 a1 = *(const bh8*)(Bp + (size_t)kt * NROW + 8);
        #pragma unroll
        for (int q = 0; q < 8; q++) {
            sB[(mc + q) * 40 + kk] = (ushort_t)a0[q];
            sB[(mc + 8 + q) * 40 + kk] = (ushort_t)a1[q];
        }
        __syncthreads();
        bh8 af[3], wf[2];
        #pragma unroll
        for (int i = 0; i < 3; i++)
            af[i] = *(const bh8*)(&sW[(i * 16 + (lane & 15)) * 40 + (lane >> 4) * 8]);
        #pragma unroll
        for (int j = 0; j < 2; j++)
            wf[j] = *(const bh8*)(&sB[(wc * 32 + j * 16 + (lane & 15)) * 40 + (lane >> 4) * 8]);
        #pragma unroll
        for (int i = 0; i < 3; i++)
            #pragma unroll
            for (int j = 0; j < 2; j++)
                acc[i][j] = __builtin_amdgcn_mfma_f32_16x16x32_bf16(af[i], wf[j], acc[i][j], 0, 0, 0);
    }

    #pragma unroll
    for (int i = 0; i < 3; i++) {
        #pragma unroll
        for (int j = 0; j < 2; j++) {
            const int nb = i * 16 + (lane >> 4) * 4;
            const int mm = m0 + wc * 32 + j * 16 + (lane & 15);
            #pragma unroll
            for (int r = 0; r < 4; r++)
                dbl[(size_t)(nb + r) * NROW + mm] = acc[i][j][r];
        }
    }
}

// ---------------- delta = softplus(dt @ dt_w^T + dt_b), transposed I/O ----------------
__global__ __launch_bounds__(256) void delta_kernel(
    const float* __restrict__ dblT0, const float* __restrict__ dblT1,
    const float* __restrict__ dtw0, const float* __restrict__ dtw1,
    const float* __restrict__ dtb0, const float* __restrict__ dtb1,
    ushort_t* __restrict__ delT0, ushort_t* __restrict__ delT1) {
    const int e = blockIdx.z;
    const float* __restrict__ dblT = e ? dblT1 : dblT0;
    const float* __restrict__ dtw = e ? dtw1 : dtw0;
    const float* __restrict__ dtb = e ? dtb1 : dtb0;
    ushort_t* __restrict__ delT = e ? delT1 : delT0;

    const int tid = threadIdx.x, lane = tid & 63, wv = tid >> 6;
    const int bx = blockIdx.x;
    const int d = (bx & 127) * 4 + wv;
    const int m0 = (bx >> 7) * 256 + lane * 4;

    const float bias = dtb[d];
    f32x4 acc = {bias, bias, bias, bias};
    #pragma unroll
    for (int k = 0; k < 16; k++) {
        const float wk = dtw[d * 16 + k];
        const f32x4 bv = *(const f32x4*)(dblT + (size_t)k * NROW + m0);
        #pragma unroll
        for (int c = 0; c < 4; c++) acc[c] = fmaf(wk, bv[c], acc[c]);
    }
    float sp[4];
    #pragma unroll
    for (int c = 0; c < 4; c++) {
        const float x = acc[c];
        sp[c] = (x > 20.0f) ? x : 0.69314718f * flog2(1.0f + fexp2(1.44269504f * x));
    }
    u32x2 r;
    r[0] = cvtpk(sp[0], sp[1]);
    r[1] = cvtpk(sp[2], sp[3]);
    *(u32x2*)(&delT[(size_t)d * NROW + m0]) = r;
}

// ---------------- selective scan: LDS-staged dT/uT (64 steps ahead), XCD swizzle ----------------
// yT aliases delT arena (write of chunk c happens after stage-read of chunk c+1 issued).
__global__ __launch_bounds__(256) void scan_kernel(
    const ushort_t* delT0, const ushort_t* delT1,               // alias yT: no restrict
    const ushort_t* __restrict__ ucT0, const ushort_t* __restrict__ ucT1,
    const float* __restrict__ dblT0, const float* __restrict__ dblT1,
    const float* __restrict__ al0, const float* __restrict__ al1,
    const float* __restrict__ Dp0, const float* __restrict__ Dp1,
    ushort_t* y0, ushort_t* y1) {
    // XCD-aware decomposition: each XCD owns 4 (e,b) combos exclusively so the
    // shared B/C rows (262 KB per combo) stay L2-resident. Any permutation is
    // correct; mapping only affects locality.
    const int gid = blockIdx.x;            // [0,1024)
    const int xcd = gid & 7;
    const int k = gid >> 3;                // [0,128)
    const int combo = xcd * 4 + (k >> 5);  // [0,32)
    const int dtile = k & 31;
    const int e = combo & 1;
    const int b = combo >> 1;

    const ushort_t* delT = e ? delT1 : delT0;
    const ushort_t* __restrict__ ucT = e ? ucT1 : ucT0;
    const float* __restrict__ dbl = e ? dblT1 : dblT0;
    const float* __restrict__ al = e ? al1 : al0;
    const float* __restrict__ Dq = e ? Dp1 : Dp0;
    ushort_t* yo = e ? y1 : y0;

    const int tid = threadIdx.x;
    const int s = tid & 15;
    const int dloc = tid >> 4;
    const int d = dtile * 16 + dloc;

    // double-buffered stage: [16 d][64 t] bf16 = 2 KB per array per buffer
    __shared__ ushort_t sD[2][16 * 64];
    __shared__ ushort_t sU[2][16 * 64];

    // staging roles: waves 0,1 -> sD rows 0-7 / 8-15; waves 2,3 -> sU.
    // LDS layout [16][64] row-major makes dest exactly wave_base + lane*16.
    const int st_row = (tid >> 3) & 15;
    const ushort_t* st_src = ((tid >> 7) ? ucT : delT)
        + (size_t)(dtile * 16 + st_row) * NROW + b * LEN + (tid & 7) * 8;
    const int st_off = ((tid >> 6) & 1) * 512;   // +1024 B for odd waves

    const float A2 = -expf(al[(d << 4) + s]) * 1.44269504f;
    const float Dpv16 = Dq[d] * 0.0625f;         // exact pow2 pre-scale for pre-reduce fold

    const float* Bp = dbl + (size_t)(16 + s) * NROW + b * LEN;
    const float* Cp = dbl + (size_t)(32 + s) * NROW + b * LEN;
    ushort_t* yp = yo + (size_t)d * NROW + b * LEN;

    // prologue: stage chunk 0; prefetch B/C for t=0..7
    gload16(st_src, ((tid >> 7) ? sU[0] : sD[0]) + st_off);
    f32x4 B0 = *(const f32x4*)Bp, B1 = *(const f32x4*)(Bp + 4);
    f32x4 C0 = *(const f32x4*)Cp, C1 = *(const f32x4*)(Cp + 4);
    __syncthreads();   // drains the stage (compiler emits vmcnt(0) before barrier)

    float h = 0.f;
    u32x4 osv;
    for (int sup = 0; sup < 32; sup++) {
        const int q = sup & 1;
        if (sup + 1 < 32)   // stage next 64-step chunk into the other buffer
            gload16(st_src + (sup + 1) * 64, ((tid >> 7) ? sU[q ^ 1] : sD[q ^ 1]) + st_off);
        #pragma unroll
        for (int sub = 0; sub < 8; sub++) {
            const int t0 = sup * 64 + sub * 8;
            // rolling B/C prefetch (final iter reads 64 B of slack inside the arena)
            f32x4 Bn0 = *(const f32x4*)(Bp + t0 + 8), Bn1 = *(const f32x4*)(Bp + t0 + 12);
            f32x4 Cn0 = *(const f32x4*)(Cp + t0 + 8), Cn1 = *(const f32x4*)(Cp + t0 + 12);
            const bh8 dv = *(const bh8*)(&sD[q][dloc * 64 + sub * 8]);   // 16-lane broadcast
            const bh8 uv = *(const bh8*)(&sU[q][dloc * 64 + sub * 8]);
            float yv[8];
            #pragma unroll
            for (int j = 0; j < 8; j++) {
                const float dt = b2f((ushort_t)dv[j]);
                const float uf = b2f((ushort_t)uv[j]);
                const float Bj = (j < 4) ? B0[j] : B1[j - 4];
                const float Cj = (j < 4) ? C0[j] : C1[j - 4];
                h = fmaf(h, fexp2(dt * A2), dt * uf * Bj);
                yv[j] = fmaf(uf, Dpv16, h * Cj);   // 16 lanes each add uf*Dp/16 -> sums to uf*Dp
            }
            #pragma unroll
            for (int j = 0; j < 8; j++) yv[j] = bsum16(yv[j]);
            osv[sub & 1 ? 1 : 0] = cvtpk(yv[0], yv[1]);   // placeholder overwritten below
            // pack 8 outputs into 16 B; buffer 2 subiters -> flush 32 B; buffer 4 -> 64 B
            u32x4 o;
            #pragma unroll
            for (int kk = 0; kk < 4; kk++)
                o[kk] = cvtpk(yv[2 * kk], yv[2 * kk + 1]);
            if (s == 0) *(u32x4*)(yp + t0) = o;
            B0 = Bn0; B1 = Bn1; C0 = Cn0; C1 = Cn1;
        }
        __syncthreads();   // buffer q consumed by all waves; next stage complete
    }
}

// ---------------- gate: ygT = yT * silu(zT), elementwise, in-place over zT ----------------
__global__ __launch_bounds__(256) void gate_kernel(
    const ushort_t* __restrict__ yT0, const ushort_t* __restrict__ yT1,
    ushort_t* zg0, ushort_t* zg1) {
    const int e = blockIdx.z;
    const ushort_t* __restrict__ yv = e ? yT1 : yT0;
    ushort_t* zg = e ? zg1 : zg0;
    const size_t i8 = ((size_t)blockIdx.x * 256 + threadIdx.x) * 8;
    bh8 y8 = *(const bh8*)(yv + i8);
    bh8 z8 = *(const bh8*)(zg + i8);
    float p[8];
    #pragma unroll
    for (int j = 0; j < 8; j++)
        p[j] = b2f((ushort_t)y8[j]) * silu(b2f((ushort_t)z8[j]));
    u32x4 o;
    #pragma unroll
    for (int k = 0; k < 4; k++) o[k] = cvtpk(p[2 * k], p[2 * k + 1]);
    *(u32x4*)(zg + i8) = o;
}

// ---------------- out-proj GEMM: o = yg @ out_w^T + residual (fp32) ----------------
__global__ __launch_bounds__(256) void gemm_out_kernel(
    const ushort_t* __restrict__ ygT0, const ushort_t* __restrict__ ygT1,
    const ushort_t* __restrict__ Wb0, const ushort_t* __restrict__ Wb1,
    const float* __restrict__ r0, const float* __restrict__ r1,
    float* __restrict__ o0, float* __restrict__ o1) {
    const int e = blockIdx.z;
    const ushort_t* __restrict__ ygT = e ? ygT1 : ygT0;
    const ushort_t* __restrict__ W = (e ? Wb1 : Wb0) + WB_OUT;
    const float* __restrict__ rr = e ? r1 : r0;
    float* __restrict__ oo = e ? o1 : o0;
    const int m0 = blockIdx.x * 128;
    const int n0 = blockIdx.y * 128;
    const int tid = threadIdx.x, lane = tid & 63, wv = tid >> 6;
    const int wr = wv >> 1, wc = wv & 1;

    __shared__ ushort_t sA[128 * 40];
    __shared__ ushort_t sW[128 * 32];

    f32x4 acc[4][4];
    #pragma unroll
    for (int i = 0; i < 4; i++)
        #pragma unroll
        for (int j = 0; j < 4; j++) acc[i][j] = (f32x4){0.f, 0.f, 0.f, 0.f};

    const int kk = tid >> 3, mc = (tid & 7) * 16;
    const ushort_t* Yp = ygT + (size_t)kk * NROW + m0 + mc;
    const ushort_t* Wp = W + (size_t)(n0 + wv * 32 + (lane >> 2)) * 512 + (lane & 3) * 8;

    for (int kt = 0; kt < 512; kt += 32) {
        __syncthreads();
        gload16(Wp + kt,             &sW[(wv * 32) * 32]);
        gload16(Wp + kt + 16 * 512,  &sW[(wv * 32 + 16) * 32]);
        bh8 a0 = *(const bh8*)(Yp + (size_t)kt * NROW);
        bh8 a1 = *(const bh8*)(Yp + (size_t)kt * NROW + 8);
        #pragma unroll
        for (int q = 0; q < 8; q++) {
            sA[(mc + q) * 40 + kk] = (ushort_t)a0[q];
            sA[(mc + 8 + q) * 40 + kk] = (ushort_t)a1[q];
        }
        __syncthreads();
        bh8 af[4], wf[4];
        #pragma unroll
        for (int i = 0; i < 4; i++)
            af[i] = *(const bh8*)(&sA[(wr * 64 + i * 16 + (lane & 15)) * 40 + (lane >> 4) * 8]);
        #pragma unroll
        for (int j = 0; j < 4; j++)
            wf[j] = *(const bh8*)(&sW[(wc * 64 + j * 16 + (lane & 15)) * 32 + (lane >> 4) * 8]);
        #pragma unroll
        for (int i = 0; i < 4; i++)
            #pragma unroll
            for (int j = 0; j < 4; j++)
                acc[i][j] = __builtin_amdgcn_mfma_f32_16x16x32_bf16(af[i], wf[j], acc[i][j], 0, 0, 0);
    }

    #pragma unroll
    for (int i = 0; i < 4; i++) {
        #pragma unroll
        for (int j = 0; j < 4; j++) {
            const int rbase = m0 + wr * 64 + i * 16 + (lane >> 4) * 4;
            const int col = n0 + wc * 64 + j * 16 + (lane & 15);
            #pragma unroll
            for (int r = 0; r < 4; r++) {
                const size_t off = (size_t)(rbase + r) * DIM + col;
                oo[off] = acc[i][j][r] + rr[off];
            }
        }
    }
}

extern "C" void kernel_launch(void* const* d_in, const int* in_sizes, int n_in,
                              void* d_out, int out_size, void* d_ws, size_t ws_size,
                              hipStream_t stream) {
    const float* x1    = (const float*)d_in[0];
    const float* x2    = (const float*)d_in[1];
    const float* ratio = (const float*)d_in[2];
    const float* ln1w  = (const float*)d_in[3];
    const float* ln1b  = (const float*)d_in[4];
    const float* ln2w  = (const float*)d_in[5];
    const float* ln2b  = (const float*)d_in[6];
    const float* inw[2]   = {(const float*)d_in[7],  (const float*)d_in[16]};
    const float* convw[2] = {(const float*)d_in[8],  (const float*)d_in[17]};
    const float* convb[2] = {(const float*)d_in[9],  (const float*)d_in[18]};
    const float* xprw[2]  = {(const float*)d_in[10], (const float*)d_in[19]};
    const float* dtw[2]   = {(const float*)d_in[11], (const float*)d_in[20]};
    const float* dtb[2]   = {(const float*)d_in[12], (const float*)d_in[21]};
    const float* alog[2]  = {(const float*)d_in[13], (const float*)d_in[22]};
    const float* Dp[2]    = {(const float*)d_in[14], (const float*)d_in[23]};
    const float* outw[2]  = {(const float*)d_in[15], (const float*)d_in[24]};

    // d_out map (fp32 o1 | o2): xs[e] bf16 @ bytes [0,16.78M) of each half;
    // dbl[e] f32 @ [16.78M, 23.07M). All dead before out-proj writes.
    float* o1 = (float*)d_out;
    float* o2 = o1 + (size_t)NROW * DIM;
    ushort_t* xs[2] = {(ushort_t*)o1, (ushort_t*)o2};
    const size_t XS_BYTES = (size_t)NROW * DIM * 2;
    float* dbl[2] = {(float*)((char*)o1 + XS_BYTES), (float*)((char*)o2 + XS_BYTES)};

    // ws arenas (~203 MB): uT[2] (-> delT -> yT), zT[2] (-> ygT), ucT[2], wbf[2]
    const size_t SZ_DI = (size_t)NROW * DI * 2;
    const size_t SZ_WB = ((size_t)WB_TOT * 2 + 255) & ~(size_t)255;
    char* p = (char*)d_ws;
    ushort_t* uT[2]  = {(ushort_t*)p, (ushort_t*)(p + SZ_DI)};            p += 2 * SZ_DI;
    ushort_t* zT[2]  = {(ushort_t*)p, (ushort_t*)(p + SZ_DI)};            p += 2 * SZ_DI;
    ushort_t* ucT[2] = {(ushort_t*)p, (ushort_t*)(p + SZ_DI)};            p += 2 * SZ_DI;
    ushort_t* wbf[2] = {(ushort_t*)p, (ushort_t*)(p + SZ_WB)};
    ushort_t* delT[2] = {uT[0], uT[1]};   // uT dead after conv
    ushort_t* yT[2]   = {uT[0], uT[1]};   // scan writes yT over delT
    ushort_t* ygT[2]  = {zT[0], zT[1]};   // gate writes yg over zT

    ln_swap_kernel<<<NROW, 256, 0, stream>>>(x1, x2, ratio, ln1w, ln1b, ln2w, ln2b, xs[0], xs[1]);

    cvtw_kernel<<<dim3(WB_TOT / 256, 1, 2), 256, 0, stream>>>(
        inw[0], inw[1], xprw[0], xprw[1], outw[0], outw[1], wbf[0], wbf[1]);

    gemm_in_kernel<<<dim3(NROW / 128, 8, 2), 256, 0, stream>>>(
        xs[0], xs[1], wbf[0], wbf[1], uT[0], uT[1], zT[0], zT[1]);

    conv_silu_kernel<<<dim3((DI * NCHUNK) / 256, 1, 2), 256, 0, stream>>>(
        uT[0], uT[1], convw[0], convw[1], convb[0], convb[1], ucT[0], ucT[1]);

    gemm_xp_kernel<<<dim3(NROW / 128, 1, 2), 256, 0, stream>>>(
        ucT[0], ucT[1], wbf[0], wbf[1], dbl[0], dbl[1]);

    delta_kernel<<<dim3(128 * 128, 1, 2), 256, 0, stream>>>(
        dbl[0], dbl[1], dtw[0], dtw[1], dtb[0], dtb[1], delT[0], delT[1]);

    scan_kernel<<<dim3(1024), 256, 0, stream>>>(
        delT[0], delT[1], ucT[0], ucT[1], dbl[0], dbl[1],
        alog[0], alog[1], Dp[0], Dp[1], yT[0], yT[1]);

    gate_kernel<<<dim3((NROW * DI / 8) / 256, 1, 2), 256, 0, stream>>>(
        yT[0], yT[1], ygT[0], ygT[1]);

    gemm_out_kernel<<<dim3(NROW / 128, 2, 2), 256, 0, stream>>>(
        ygT[0], ygT[1], wbf[0], wbf[1], x1, x2, o1, o2);
}

// Round 8
// 567.368 us; speedup vs baseline: 3.9021x; 1.4119x over previous
//
#include <hip/hip_runtime.h>

typedef unsigned short ushort_t;
typedef __attribute__((ext_vector_type(8))) short bh8;
typedef __attribute__((ext_vector_type(4))) float f32x4;
typedef __attribute__((ext_vector_type(2))) unsigned int u32x2;
typedef __attribute__((ext_vector_type(4))) unsigned int u32x4;

#define DIM 256
#define DI 512
#define LEN 2048
#define BATCH 16
#define NROW (BATCH * LEN)   // 32768
#define NCHUNK (NROW / 8)

__device__ __forceinline__ float b2f(ushort_t u) {
    union { unsigned int i; float f; } v; v.i = ((unsigned int)u) << 16; return v.f;
}
__device__ __forceinline__ ushort_t f2b(float f) {
    union { float ff; unsigned int i; } v; v.ff = f;
    unsigned int x = v.i;
    x += 0x7fffu + ((x >> 16) & 1u);
    return (ushort_t)(x >> 16);
}
// raw transcendentals (1 instr each; no libm edge-handling)
__device__ __forceinline__ float fexp2(float x) { float r; asm("v_exp_f32 %0, %1" : "=v"(r) : "v"(x)); return r; }
__device__ __forceinline__ float flog2(float x) { float r; asm("v_log_f32 %0, %1" : "=v"(r) : "v"(x)); return r; }
__device__ __forceinline__ float frcp (float x) { float r; asm("v_rcp_f32 %0, %1" : "=v"(r) : "v"(x)); return r; }
// pack 2 f32 -> 2 bf16 (RNE), 1 instr
__device__ __forceinline__ unsigned int cvtpk(float lo, float hi) {
    unsigned int r; asm("v_cvt_pk_bf16_f32 %0, %1, %2" : "=v"(r) : "v"(lo), "v"(hi)); return r;
}
// silu without f32 division: x * rcp(1 + exp2(-log2e * x))
__device__ __forceinline__ float silu(float x) {
    return x * frcp(1.0f + fexp2(-1.44269504f * x));
}
// 16-lane butterfly sum, 4 single-instr DPP adds; all lanes end with the sum
__device__ __forceinline__ float bsum16(float v) {
    float t;
    asm("v_add_f32_dpp %0, %1, %1 quad_perm:[1,0,3,2] row_mask:0xf bank_mask:0xf" : "=v"(t) : "v"(v));
    asm("v_add_f32_dpp %0, %1, %1 quad_perm:[2,3,0,1] row_mask:0xf bank_mask:0xf" : "=v"(v) : "v"(t));
    asm("v_add_f32_dpp %0, %1, %1 row_half_mirror row_mask:0xf bank_mask:0xf" : "=v"(t) : "v"(v));
    asm("v_add_f32_dpp %0, %1, %1 row_mirror row_mask:0xf bank_mask:0xf" : "=v"(v) : "v"(t));
    return v;
}
__device__ __forceinline__ void gload16(const void* g, void* l) {
    __builtin_amdgcn_global_load_lds((const __attribute__((address_space(1))) unsigned int*)g,
                                     (__attribute__((address_space(3))) unsigned int*)l, 16, 0, 0);
}

// ---------------- LayerNorm + channel swap (fp32 in -> bf16 out) ----------------
__global__ __launch_bounds__(256) void ln_swap_kernel(
    const float* __restrict__ x1, const float* __restrict__ x2,
    const float* __restrict__ ratio,
    const float* __restrict__ ln1w, const float* __restrict__ ln1b,
    const float* __restrict__ ln2w, const float* __restrict__ ln2b,
    ushort_t* __restrict__ xs1, ushort_t* __restrict__ xs2) {
    const int m = blockIdx.x;
    const int c = threadIdx.x;
    const size_t off = (size_t)m * DIM + c;
    float v1 = x1[off];
    float v2 = x2[off];
    float s1 = v1, q1 = v1 * v1, s2 = v2, q2 = v2 * v2;
    #pragma unroll
    for (int o = 32; o; o >>= 1) {
        s1 += __shfl_xor(s1, o); q1 += __shfl_xor(q1, o);
        s2 += __shfl_xor(s2, o); q2 += __shfl_xor(q2, o);
    }
    __shared__ float red[4][4];
    const int w = threadIdx.x >> 6;
    if ((threadIdx.x & 63) == 0) { red[w][0] = s1; red[w][1] = q1; red[w][2] = s2; red[w][3] = q2; }
    __syncthreads();
    s1 = red[0][0] + red[1][0] + red[2][0] + red[3][0];
    q1 = red[0][1] + red[1][1] + red[2][1] + red[3][1];
    s2 = red[0][2] + red[1][2] + red[2][2] + red[3][2];
    q2 = red[0][3] + red[1][3] + red[2][3] + red[3][3];
    const float inv = 1.0f / DIM;
    float mu1 = s1 * inv, mu2 = s2 * inv;
    float r1 = rsqrtf(q1 * inv - mu1 * mu1 + 1e-5f);
    float r2 = rsqrtf(q2 * inv - mu2 * mu2 + 1e-5f);
    float n1 = (v1 - mu1) * r1 * ln1w[c] + ln1b[c];
    float n2 = (v2 - mu2) * r2 * ln2w[c] + ln2b[c];
    int nc = (int)(DIM / (1.0f + expf(-ratio[0])));   // = 159
    xs2[off] = f2b(n2);
    xs1[off] = f2b(c < nc ? n2 : n1);
}

// ---------------- convert weights fp32 -> bf16 (once per call) ----------------
#define WB_IN 0
#define WB_XP 262144
#define WB_OUT 286720
#define WB_TOT 417792
__global__ __launch_bounds__(256) void cvtw_kernel(
    const float* __restrict__ iw0, const float* __restrict__ iw1,
    const float* __restrict__ xw0, const float* __restrict__ xw1,
    const float* __restrict__ ow0, const float* __restrict__ ow1,
    ushort_t* __restrict__ o0, ushort_t* __restrict__ o1) {
    const int e = blockIdx.z;
    const float* iw = e ? iw1 : iw0;
    const float* xw = e ? xw1 : xw0;
    const float* ow = e ? ow1 : ow0;
    ushort_t* o = e ? o1 : o0;
    const int idx = blockIdx.x * 256 + threadIdx.x;
    if (idx < WB_XP) o[idx] = f2b(iw[idx]);
    else if (idx < WB_OUT) o[idx] = f2b(xw[idx - WB_XP]);
    else if (idx < WB_TOT) o[idx] = f2b(ow[idx - WB_OUT]);
}

// ---------------- in-proj GEMM: [u|z] = xs @ in_w^T ; outputs TRANSPOSED ----------------
__global__ __launch_bounds__(256) void gemm_in_kernel(
    const ushort_t* __restrict__ A0, const ushort_t* __restrict__ A1,
    const ushort_t* __restrict__ Wb0, const ushort_t* __restrict__ Wb1,
    ushort_t* __restrict__ uT0, ushort_t* __restrict__ uT1,
    ushort_t* __restrict__ zT0, ushort_t* __restrict__ zT1) {
    const int e = blockIdx.z;
    const ushort_t* __restrict__ A = e ? A1 : A0;
    const ushort_t* __restrict__ W = e ? Wb1 : Wb0;
    ushort_t* __restrict__ uT = e ? uT1 : uT0;
    ushort_t* __restrict__ zT = e ? zT1 : zT0;
    const int m0 = blockIdx.x * 128;
    const int n0 = blockIdx.y * 128;
    const int tid = threadIdx.x, lane = tid & 63, wv = tid >> 6;
    const int wr = wv >> 1, wc = wv & 1;

    __shared__ ushort_t sA[128 * 32];
    __shared__ ushort_t sW[128 * 32];

    f32x4 acc[4][4];
    #pragma unroll
    for (int i = 0; i < 4; i++)
        #pragma unroll
        for (int j = 0; j < 4; j++) acc[i][j] = (f32x4){0.f, 0.f, 0.f, 0.f};

    const ushort_t* Ap = A + (size_t)(m0 + wv * 32 + (lane >> 2)) * 256 + (lane & 3) * 8;
    const ushort_t* Wp = W + (size_t)(n0 + wv * 32 + (lane >> 2)) * 256 + (lane & 3) * 8;

    for (int kt = 0; kt < 256; kt += 32) {
        __syncthreads();
        gload16(Ap + kt,             &sA[(wv * 32) * 32]);
        gload16(Ap + kt + 16 * 256,  &sA[(wv * 32 + 16) * 32]);
        gload16(Wp + kt,             &sW[(wv * 32) * 32]);
        gload16(Wp + kt + 16 * 256,  &sW[(wv * 32 + 16) * 32]);
        __syncthreads();
        bh8 af[4], wf[4];
        #pragma unroll
        for (int i = 0; i < 4; i++)
            af[i] = *(const bh8*)(&sA[(wr * 64 + i * 16 + (lane & 15)) * 32 + (lane >> 4) * 8]);
        #pragma unroll
        for (int j = 0; j < 4; j++)
            wf[j] = *(const bh8*)(&sW[(wc * 64 + j * 16 + (lane & 15)) * 32 + (lane >> 4) * 8]);
        #pragma unroll
        for (int i = 0; i < 4; i++)
            #pragma unroll
            for (int j = 0; j < 4; j++)
                acc[i][j] = __builtin_amdgcn_mfma_f32_16x16x32_bf16(af[i], wf[j], acc[i][j], 0, 0, 0);
    }

    #pragma unroll
    for (int i = 0; i < 4; i++) {
        #pragma unroll
        for (int j = 0; j < 4; j++) {
            const int rbase = m0 + wr * 64 + i * 16 + (lane >> 4) * 4;
            const int col = n0 + wc * 64 + j * 16 + (lane & 15);
            u32x2 vv;
            vv[0] = cvtpk(acc[i][j][0], acc[i][j][1]);
            vv[1] = cvtpk(acc[i][j][2], acc[i][j][3]);
            if (col < DI) *(u32x2*)(&uT[(size_t)col * NROW + rbase]) = vv;
            else          *(u32x2*)(&zT[(size_t)(col - DI) * NROW + rbase]) = vv;
        }
    }
}

// ---------------- causal depthwise conv4 + SiLU, time-major ----------------
__global__ __launch_bounds__(256) void conv_silu_kernel(
    const ushort_t* __restrict__ uT0, const ushort_t* __restrict__ uT1,
    const float* __restrict__ cw0, const float* __restrict__ cw1,
    const float* __restrict__ cb0, const float* __restrict__ cb1,
    ushort_t* __restrict__ ucT0, ushort_t* __restrict__ ucT1) {
    const int e = blockIdx.z;
    const ushort_t* __restrict__ uT = e ? uT1 : uT0;
    const float* __restrict__ cw = e ? cw1 : cw0;
    const float* __restrict__ cb = e ? cb1 : cb0;
    ushort_t* __restrict__ ucT = e ? ucT1 : ucT0;

    const int g = blockIdx.x * 256 + threadIdx.x;
    const int c = g & (NCHUNK - 1);
    const int d = g >> 12;
    const int b = c >> 8;
    const int t0 = (c & 255) * 8;
    const size_t base = (size_t)d * NROW + b * LEN + t0;

    bh8 cur = *(const bh8*)(uT + base);
    float win[11];
    if (t0) {
        win[0] = b2f(uT[base - 3]); win[1] = b2f(uT[base - 2]); win[2] = b2f(uT[base - 1]);
    } else {
        win[0] = 0.f; win[1] = 0.f; win[2] = 0.f;
    }
    #pragma unroll
    for (int j = 0; j < 8; j++) win[3 + j] = b2f((ushort_t)cur[j]);
    const f32x4 w = *(const f32x4*)(cw + d * 4);
    const float bias = cb[d];
    float s[8];
    #pragma unroll
    for (int j = 0; j < 8; j++) {
        const float a = bias + w[0] * win[j] + w[1] * win[j + 1] + w[2] * win[j + 2] + w[3] * win[j + 3];
        s[j] = silu(a);
    }
    u32x4 o;
    #pragma unroll
    for (int k = 0; k < 4; k++) o[k] = cvtpk(s[2 * k], s[2 * k + 1]);
    *(u32x4*)(ucT + base) = o;
}

// ---------------- x-proj GEMM: rows 0..15 -> dblT[n][m]; rows 16..47 -> BCt[m][32] ----------------
__global__ __launch_bounds__(256) void gemm_xp_kernel(
    const ushort_t* __restrict__ ucT0, const ushort_t* __restrict__ ucT1,
    const ushort_t* __restrict__ Wb0, const ushort_t* __restrict__ Wb1,
    float* __restrict__ dbl0, float* __restrict__ dbl1,
    float* __restrict__ BCt0, float* __restrict__ BCt1) {
    const int e = blockIdx.z;
    const ushort_t* __restrict__ ucT = e ? ucT1 : ucT0;
    const ushort_t* __restrict__ W = (e ? Wb1 : Wb0) + WB_XP;
    float* __restrict__ dbl = e ? dbl1 : dbl0;
    float* __restrict__ BCt = e ? BCt1 : BCt0;
    const int m0 = blockIdx.x * 128;
    const int tid = threadIdx.x, lane = tid & 63;
    const int wc = tid >> 6;

    __shared__ ushort_t sW[48 * 40];
    __shared__ ushort_t sB[128 * 40];

    f32x4 acc[3][2];
    #pragma unroll
    for (int i = 0; i < 3; i++)
        #pragma unroll
        for (int j = 0; j < 2; j++) acc[i][j] = (f32x4){0.f, 0.f, 0.f, 0.f};

    const int kk = tid >> 3, mc = (tid & 7) * 16;
    const ushort_t* Bp = ucT + (size_t)kk * NROW + m0 + mc;

    for (int kt = 0; kt < 512; kt += 32) {
        __syncthreads();
        if (tid < 192) {
            const int r = tid >> 2, cc = (tid & 3) * 8;
            bh8 v = *(const bh8*)(W + (size_t)r * 512 + kt + cc);
            *(bh8*)(&sW[r * 40 + cc]) = v;
        }
        bh8 a0 = *(const bh8*)(Bp + (size_t)kt * NROW);
        bh8 a1 = *(const bh8*)(Bp + (size_t)kt * NROW + 8);
        #pragma unroll
        for (int q = 0; q < 8; q++) {
            sB[(mc + q) * 40 + kk] = (ushort_t)a0[q];
            sB[(mc + 8 + q) * 40 + kk] = (ushort_t)a1[q];
        }
        __syncthreads();
        bh8 af[3], wf[2];
        #pragma unroll
        for (int i = 0; i < 3; i++)
            af[i] = *(const bh8*)(&sW[(i * 16 + (lane & 15)) * 40 + (lane >> 4) * 8]);
        #pragma unroll
        for (int j = 0; j < 2; j++)
            wf[j] = *(const bh8*)(&sB[(wc * 32 + j * 16 + (lane & 15)) * 40 + (lane >> 4) * 8]);
        #pragma unroll
        for (int i = 0; i < 3; i++)
            #pragma unroll
            for (int j = 0; j < 2; j++)
                acc[i][j] = __builtin_amdgcn_mfma_f32_16x16x32_bf16(af[i], wf[j], acc[i][j], 0, 0, 0);
    }

    #pragma unroll
    for (int j = 0; j < 2; j++) {
        const int mm = m0 + wc * 32 + j * 16 + (lane & 15);
        {   // rows 0..15 -> dblT (delta-kernel input layout)
            const int nb = (lane >> 4) * 4;
            #pragma unroll
            for (int r = 0; r < 4; r++)
                dbl[(size_t)(nb + r) * NROW + mm] = acc[0][j][r];
        }
        #pragma unroll
        for (int i = 1; i < 3; i++) {   // rows 16..47 -> BCt[m][s] / BCt[m][16+s], 16B stores
            const int sb = (i - 1) * 16 + (lane >> 4) * 4;
            *(f32x4*)(&BCt[(size_t)mm * 32 + sb]) = acc[i][j];
        }
    }
}

// ---------------- delta = softplus(dt @ dt_w^T + dt_b), transposed I/O ----------------
__global__ __launch_bounds__(256) void delta_kernel(
    const float* __restrict__ dblT0, const float* __restrict__ dblT1,
    const float* __restrict__ dtw0, const float* __restrict__ dtw1,
    const float* __restrict__ dtb0, const float* __restrict__ dtb1,
    ushort_t* __restrict__ delT0, ushort_t* __restrict__ delT1) {
    const int e = blockIdx.z;
    const float* __restrict__ dblT = e ? dblT1 : dblT0;
    const float* __restrict__ dtw = e ? dtw1 : dtw0;
    const float* __restrict__ dtb = e ? dtb1 : dtb0;
    ushort_t* __restrict__ delT = e ? delT1 : delT0;

    const int tid = threadIdx.x, lane = tid & 63, wv = tid >> 6;
    const int bx = blockIdx.x;
    const int d = (bx & 127) * 4 + wv;
    const int m0 = (bx >> 7) * 256 + lane * 4;

    const float bias = dtb[d];
    f32x4 acc = {bias, bias, bias, bias};
    #pragma unroll
    for (int k = 0; k < 16; k++) {
        const float wk = dtw[d * 16 + k];
        const f32x4 bv = *(const f32x4*)(dblT + (size_t)k * NROW + m0);
        #pragma unroll
        for (int c = 0; c < 4; c++) acc[c] = fmaf(wk, bv[c], acc[c]);
    }
    float sp[4];
    #pragma unroll
    for (int c = 0; c < 4; c++) {
        const float x = acc[c];
        sp[c] = (x > 20.0f) ? x : 0.69314718f * flog2(1.0f + fexp2(1.44269504f * x));
    }
    u32x2 r;
    r[0] = cvtpk(sp[0], sp[1]);
    r[1] = cvtpk(sp[2], sp[3]);
    *(u32x2*)(&delT[(size_t)d * NROW + m0]) = r;
}

// ---------------- selective scan: ALL inputs LDS-staged 64 steps ahead, XCD swizzle ----------------
// yT aliases delT arena (write of chunk c happens after stage of chunk c+1 issued).
__global__ __launch_bounds__(256) void scan_kernel(
    const ushort_t* delT0, const ushort_t* delT1,               // alias yT: no restrict
    const ushort_t* __restrict__ ucT0, const ushort_t* __restrict__ ucT1,
    const float* __restrict__ BCt0, const float* __restrict__ BCt1,
    const float* __restrict__ al0, const float* __restrict__ al1,
    const float* __restrict__ Dp0, const float* __restrict__ Dp1,
    ushort_t* y0, ushort_t* y1) {
    // XCD-aware decomposition: each XCD owns 4 (e,b) combos exclusively.
    const int gid = blockIdx.x;            // [0,1024)
    const int xcd = gid & 7;
    const int k = gid >> 3;                // [0,128)
    const int combo = xcd * 4 + (k >> 5);  // [0,32)
    const int dtile = k & 31;
    const int e = combo & 1;
    const int b = combo >> 1;

    const ushort_t* delT = e ? delT1 : delT0;
    const ushort_t* __restrict__ ucT = e ? ucT1 : ucT0;
    const float* __restrict__ BCt = e ? BCt1 : BCt0;
    const float* __restrict__ al = e ? al1 : al0;
    const float* __restrict__ Dq = e ? Dp1 : Dp0;
    ushort_t* yo = e ? y1 : y0;

    const int tid = threadIdx.x;
    const int s = tid & 15;
    const int dloc = tid >> 4;
    const int d = dtile * 16 + dloc;
    const int w = tid >> 6, lane = tid & 63;

    // double-buffered chunk stage (64 timesteps):
    //   sD/sU: [16 d][64 t] bf16 (2 KB each); sBC: [64 t][32 s] f32 (8 KB)
    __shared__ ushort_t sD[2][16 * 64];
    __shared__ ushort_t sU[2][16 * 64];
    __shared__ float sBC[2][64 * 32];

    // role A: waves 0,1 stage sD rows 0-7/8-15; waves 2,3 stage sU likewise.
    const ushort_t* srcA = ((w >= 2) ? ucT : delT)
        + (size_t)(dtile * 16 + (w & 1) * 8 + (lane >> 3)) * NROW + b * LEN + (lane & 7) * 8;
    // role B: each wave stages 2 KB of the contiguous 8 KB BC chunk.
    const float* srcBC = BCt + (size_t)b * LEN * 32;

    const float A2 = -expf(al[(d << 4) + s]) * 1.44269504f;
    const float Dpv16 = Dq[d] * 0.0625f;   // exact pow2 pre-scale: 16 lanes sum to u*Dp

    ushort_t* yp = yo + (size_t)d * NROW + b * LEN;

    // prologue: stage chunk 0
    {
        ushort_t* dstA = ((w >= 2) ? sU[0] : sD[0]) + (w & 1) * 512;
        gload16(srcA, dstA);
        gload16(srcBC + (w * 2 + 0) * 256 + lane * 4, &sBC[0][(w * 2 + 0) * 256]);
        gload16(srcBC + (w * 2 + 1) * 256 + lane * 4, &sBC[0][(w * 2 + 1) * 256]);
    }
    __syncthreads();

    float h = 0.f;
    for (int sup = 0; sup < 32; sup++) {
        const int q = sup & 1;
        {   // stage chunk sup+1 into the other buffer (last iter reads arena slack; safe)
            ushort_t* dstA = ((w >= 2) ? sU[q ^ 1] : sD[q ^ 1]) + (w & 1) * 512;
            gload16(srcA + (sup + 1) * 64, dstA);
            const float* sb = srcBC + (size_t)(sup + 1) * 2048;
            gload16(sb + (w * 2 + 0) * 256 + lane * 4, &sBC[q ^ 1][(w * 2 + 0) * 256]);
            gload16(sb + (w * 2 + 1) * 256 + lane * 4, &sBC[q ^ 1][(w * 2 + 1) * 256]);
        }
        #pragma unroll
        for (int sub = 0; sub < 8; sub++) {
            const bh8 dv = *(const bh8*)(&sD[q][dloc * 64 + sub * 8]);   // 16-lane broadcast
            const bh8 uv = *(const bh8*)(&sU[q][dloc * 64 + sub * 8]);
            float yv[8];
            #pragma unroll
            for (int j = 0; j < 8; j++) {
                const float dt = b2f((ushort_t)dv[j]);
                const float uf = b2f((ushort_t)uv[j]);
                const float Bj = sBC[q][(sub * 8 + j) * 32 + s];        // banks 0..15, bcast
                const float Cj = sBC[q][(sub * 8 + j) * 32 + 16 + s];   // banks 16..31
                h = fmaf(h, fexp2(dt * A2), dt * uf * Bj);
                yv[j] = fmaf(uf, Dpv16, h * Cj);
            }
            #pragma unroll
            for (int j = 0; j < 8; j++) yv[j] = bsum16(yv[j]);
            u32x4 o;
            #pragma unroll
            for (int kk = 0; kk < 4; kk++)
                o[kk] = cvtpk(yv[2 * kk], yv[2 * kk + 1]);
            if (s == 0) *(u32x4*)(yp + sup * 64 + sub * 8) = o;
        }
        __syncthreads();   // buffer q consumed by all; stage of q^1 drained (vmcnt before barrier)
    }
}

// ---------------- gate: ygT = yT * silu(zT), elementwise, in-place over zT ----------------
__global__ __launch_bounds__(256) void gate_kernel(
    const ushort_t* __restrict__ yT0, const ushort_t* __restrict__ yT1,
    ushort_t* zg0, ushort_t* zg1) {
    const int e = blockIdx.z;
    const ushort_t* __restrict__ yv = e ? yT1 : yT0;
    ushort_t* zg = e ? zg1 : zg0;
    const size_t i8 = ((size_t)blockIdx.x * 256 + threadIdx.x) * 8;
    bh8 y8 = *(const bh8*)(yv + i8);
    bh8 z8 = *(const bh8*)(zg + i8);
    float p[8];
    #pragma unroll
    for (int j = 0; j < 8; j++)
        p[j] = b2f((ushort_t)y8[j]) * silu(b2f((ushort_t)z8[j]));
    u32x4 o;
    #pragma unroll
    for (int k = 0; k < 4; k++) o[k] = cvtpk(p[2 * k], p[2 * k + 1]);
    *(u32x4*)(zg + i8) = o;
}

// ---------------- out-proj GEMM: o = yg @ out_w^T + residual (fp32) ----------------
__global__ __launch_bounds__(256) void gemm_out_kernel(
    const ushort_t* __restrict__ ygT0, const ushort_t* __restrict__ ygT1,
    const ushort_t* __restrict__ Wb0, const ushort_t* __restrict__ Wb1,
    const float* __restrict__ r0, const float* __restrict__ r1,
    float* __restrict__ o0, float* __restrict__ o1) {
    const int e = blockIdx.z;
    const ushort_t* __restrict__ ygT = e ? ygT1 : ygT0;
    const ushort_t* __restrict__ W = (e ? Wb1 : Wb0) + WB_OUT;
    const float* __restrict__ rr = e ? r1 : r0;
    float* __restrict__ oo = e ? o1 : o0;
    const int m0 = blockIdx.x * 128;
    const int n0 = blockIdx.y * 128;
    const int tid = threadIdx.x, lane = tid & 63, wv = tid >> 6;
    const int wr = wv >> 1, wc = wv & 1;

    __shared__ ushort_t sA[128 * 40];
    __shared__ ushort_t sW[128 * 32];

    f32x4 acc[4][4];
    #pragma unroll
    for (int i = 0; i < 4; i++)
        #pragma unroll
        for (int j = 0; j < 4; j++) acc[i][j] = (f32x4){0.f, 0.f, 0.f, 0.f};

    const int kk = tid >> 3, mc = (tid & 7) * 16;
    const ushort_t* Yp = ygT + (size_t)kk * NROW + m0 + mc;
    const ushort_t* Wp = W + (size_t)(n0 + wv * 32 + (lane >> 2)) * 512 + (lane & 3) * 8;

    for (int kt = 0; kt < 512; kt += 32) {
        __syncthreads();
        gload16(Wp + kt,             &sW[(wv * 32) * 32]);
        gload16(Wp + kt + 16 * 512,  &sW[(wv * 32 + 16) * 32]);
        bh8 a0 = *(const bh8*)(Yp + (size_t)kt * NROW);
        bh8 a1 = *(const bh8*)(Yp + (size_t)kt * NROW + 8);
        #pragma unroll
        for (int q = 0; q < 8; q++) {
            sA[(mc + q) * 40 + kk] = (ushort_t)a0[q];
            sA[(mc + 8 + q) * 40 + kk] = (ushort_t)a1[q];
        }
        __syncthreads();
        bh8 af[4], wf[4];
        #pragma unroll
        for (int i = 0; i < 4; i++)
            af[i] = *(const bh8*)(&sA[(wr * 64 + i * 16 + (lane & 15)) * 40 + (lane >> 4) * 8]);
        #pragma unroll
        for (int j = 0; j < 4; j++)
            wf[j] = *(const bh8*)(&sW[(wc * 64 + j * 16 + (lane & 15)) * 32 + (lane >> 4) * 8]);
        #pragma unroll
        for (int i = 0; i < 4; i++)
            #pragma unroll
            for (int j = 0; j < 4; j++)
                acc[i][j] = __builtin_amdgcn_mfma_f32_16x16x32_bf16(af[i], wf[j], acc[i][j], 0, 0, 0);
    }

    #pragma unroll
    for (int i = 0; i < 4; i++) {
        #pragma unroll
        for (int j = 0; j < 4; j++) {
            const int rbase = m0 + wr * 64 + i * 16 + (lane >> 4) * 4;
            const int col = n0 + wc * 64 + j * 16 + (lane & 15);
            #pragma unroll
            for (int r = 0; r < 4; r++) {
                const size_t off = (size_t)(rbase + r) * DIM + col;
                oo[off] = acc[i][j][r] + rr[off];
            }
        }
    }
}

extern "C" void kernel_launch(void* const* d_in, const int* in_sizes, int n_in,
                              void* d_out, int out_size, void* d_ws, size_t ws_size,
                              hipStream_t stream) {
    const float* x1    = (const float*)d_in[0];
    const float* x2    = (const float*)d_in[1];
    const float* ratio = (const float*)d_in[2];
    const float* ln1w  = (const float*)d_in[3];
    const float* ln1b  = (const float*)d_in[4];
    const float* ln2w  = (const float*)d_in[5];
    const float* ln2b  = (const float*)d_in[6];
    const float* inw[2]   = {(const float*)d_in[7],  (const float*)d_in[16]};
    const float* convw[2] = {(const float*)d_in[8],  (const float*)d_in[17]};
    const float* convb[2] = {(const float*)d_in[9],  (const float*)d_in[18]};
    const float* xprw[2]  = {(const float*)d_in[10], (const float*)d_in[19]};
    const float* dtw[2]   = {(const float*)d_in[11], (const float*)d_in[20]};
    const float* dtb[2]   = {(const float*)d_in[12], (const float*)d_in[21]};
    const float* alog[2]  = {(const float*)d_in[13], (const float*)d_in[22]};
    const float* Dp[2]    = {(const float*)d_in[14], (const float*)d_in[23]};
    const float* outw[2]  = {(const float*)d_in[15], (const float*)d_in[24]};

    // d_out map (fp32 o1 | o2, 33.55 MB each):
    //   xs[e]  bf16 @ bytes [0, 16.78M)
    //   dbl[e] f32  @ [16.78M, 18.87M)   (16 rows x NROW)
    //   BCt[e] f32  @ [18.87M, 23.07M)   ([NROW][32] t-major B|C)
    // All dead before out-proj writes o1/o2. Scan BC staging may read up to 8KB
    // past BCt end (still inside the d_out half).
    float* o1 = (float*)d_out;
    float* o2 = o1 + (size_t)NROW * DIM;
    ushort_t* xs[2] = {(ushort_t*)o1, (ushort_t*)o2};
    const size_t XS_BYTES  = (size_t)NROW * DIM * 2;
    const size_t DBL_BYTES = (size_t)16 * NROW * 4;
    float* dbl[2] = {(float*)((char*)o1 + XS_BYTES), (float*)((char*)o2 + XS_BYTES)};
    float* BCt[2] = {(float*)((char*)o1 + XS_BYTES + DBL_BYTES),
                     (float*)((char*)o2 + XS_BYTES + DBL_BYTES)};

    // ws arenas (~203 MB): uT[2] (-> delT -> yT), zT[2] (-> ygT), ucT[2], wbf[2]
    const size_t SZ_DI = (size_t)NROW * DI * 2;
    const size_t SZ_WB = ((size_t)WB_TOT * 2 + 255) & ~(size_t)255;
    char* p = (char*)d_ws;
    ushort_t* uT[2]  = {(ushort_t*)p, (ushort_t*)(p + SZ_DI)};            p += 2 * SZ_DI;
    ushort_t* zT[2]  = {(ushort_t*)p, (ushort_t*)(p + SZ_DI)};            p += 2 * SZ_DI;
    ushort_t* ucT[2] = {(ushort_t*)p, (ushort_t*)(p + SZ_DI)};            p += 2 * SZ_DI;
    ushort_t* wbf[2] = {(ushort_t*)p, (ushort_t*)(p + SZ_WB)};
    ushort_t* delT[2] = {uT[0], uT[1]};   // uT dead after conv
    ushort_t* yT[2]   = {uT[0], uT[1]};   // scan writes yT over delT
    ushort_t* ygT[2]  = {zT[0], zT[1]};   // gate writes yg over zT

    ln_swap_kernel<<<NROW, 256, 0, stream>>>(x1, x2, ratio, ln1w, ln1b, ln2w, ln2b, xs[0], xs[1]);

    cvtw_kernel<<<dim3(WB_TOT / 256, 1, 2), 256, 0, stream>>>(
        inw[0], inw[1], xprw[0], xprw[1], outw[0], outw[1], wbf[0], wbf[1]);

    gemm_in_kernel<<<dim3(NROW / 128, 8, 2), 256, 0, stream>>>(
        xs[0], xs[1], wbf[0], wbf[1], uT[0], uT[1], zT[0], zT[1]);

    conv_silu_kernel<<<dim3((DI * NCHUNK) / 256, 1, 2), 256, 0, stream>>>(
        uT[0], uT[1], convw[0], convw[1], convb[0], convb[1], ucT[0], ucT[1]);

    gemm_xp_kernel<<<dim3(NROW / 128, 1, 2), 256, 0, stream>>>(
        ucT[0], ucT[1], wbf[0], wbf[1], dbl[0], dbl[1], BCt[0], BCt[1]);

    delta_kernel<<<dim3(128 * 128, 1, 2), 256, 0, stream>>>(
        dbl[0], dbl[1], dtw[0], dtw[1], dtb[0], dtb[1], delT[0], delT[1]);

    scan_kernel<<<dim3(1024), 256, 0, stream>>>(
        delT[0], delT[1], ucT[0], ucT[1], BCt[0], BCt[1],
        alog[0], alog[1], Dp[0], Dp[1], yT[0], yT[1]);

    gate_kernel<<<dim3((NROW * DI / 8) / 256, 1, 2), 256, 0, stream>>>(
        yT[0], yT[1], ygT[0], ygT[1]);

    gemm_out_kernel<<<dim3(NROW / 128, 2, 2), 256, 0, stream>>>(
        ygT[0], ygT[1], wbf[0], wbf[1], x1, x2, o1, o2);
}